// Round 4
// baseline (606.446 us; speedup 1.0000x reference)
//
#include <hip/hip_runtime.h>
#include <math.h>

#define D_MODEL 2048
#define HEADS 32
#define HEAD_DIM 64
#define STATE 256
#define KCONV 4
#define CHUNK 64
#define NC 32            // SEQ / CHUNK
#define SEQL 2048
#define BATCHN 2
#define CONV_DIMN 2560   // D_MODEL + 2*STATE
#define PROJ_DIM 4640    // D_MODEL + CONV_DIM + HEADS
#define PROJB_W 4608     // 36*128: z + xBC cols (dt handled by dt_gemm)
#define EPSF 1e-5f
#define BL (BATCHN * SEQL)  // 4096 token rows

typedef __attribute__((ext_vector_type(8))) short short8;
typedef __attribute__((ext_vector_type(4))) short short4v;
typedef __attribute__((ext_vector_type(4))) float f32x4;

__device__ __forceinline__ short f2bf(float f) {
  unsigned u = __builtin_bit_cast(unsigned, f);
  u = (u + 0x7fffu + ((u >> 16) & 1u)) >> 16;   // RNE
  return (short)u;
}
__device__ __forceinline__ float b2f(short s) {
  unsigned u = ((unsigned)(unsigned short)s) << 16;
  return __builtin_bit_cast(float, u);
}
__device__ __forceinline__ void gld16(const void* g, void* l) {
  __builtin_amdgcn_global_load_lds((const __attribute__((address_space(1))) unsigned int*)g,
                                   (__attribute__((address_space(3))) unsigned int*)l,
                                   16, 0, 0);
}

// ---------------- transpose + fp32->bf16 -----------------------------------
__global__ __launch_bounds__(256) void transpose_bf16_k(const float* __restrict__ W,
                                                        short* __restrict__ WT,
                                                        int K, int ncols, int stride) {
  __shared__ float tile[32][33];
  int bn = blockIdx.x * 32, bk = blockIdx.y * 32;
  int tx = threadIdx.x & 31, ty = threadIdx.x >> 5;  // ty 0..7
  #pragma unroll
  for (int i = 0; i < 32; i += 8) {
    int k = bk + ty + i, n = bn + tx;
    tile[ty + i][tx] = (n < ncols) ? W[(size_t)k * stride + n] : 0.f;
  }
  __syncthreads();
  #pragma unroll
  for (int i = 0; i < 32; i += 8) {
    int n = bn + ty + i, k = bk + tx;
    WT[(size_t)n * K + k] = f2bf(tile[tx][ty + i]);
  }
}

// ------- fused RMSNorm: writes xnb (bf16 normalized row) + dtraw -----------
__global__ __launch_bounds__(256) void dt_gemm_k(const float* __restrict__ x,
                                                 const float* __restrict__ norm_w,
                                                 const float* __restrict__ w_in,
                                                 short* __restrict__ xnb,
                                                 float* __restrict__ dtraw) {
  int row = blockIdx.x;
  int t = threadIdx.x;
  __shared__ float sx[D_MODEL];
  __shared__ float red[8][32];
  __shared__ float sred[4];
  const float4* x4 = (const float4*)(x + (size_t)row * D_MODEL);
  const float4* nw4 = (const float4*)norm_w;
  float ss = 0.f;
  for (int i = t; i < D_MODEL / 4; i += 256) {
    float4 v = x4[i];
    ss += v.x * v.x + v.y * v.y + v.z * v.z + v.w * v.w;
    float4 nw = nw4[i];
    float4 pv; pv.x = v.x * nw.x; pv.y = v.y * nw.y; pv.z = v.z * nw.z; pv.w = v.w * nw.w;
    ((float4*)sx)[i] = pv;
  }
  #pragma unroll
  for (int off = 32; off > 0; off >>= 1) ss += __shfl_down(ss, off);
  if ((t & 63) == 0) sred[t >> 6] = ss;
  __syncthreads();
  float tot = sred[0] + sred[1] + sred[2] + sred[3];
  float scale = rsqrtf(tot / (float)D_MODEL + EPSF);
  // write normalized bf16 row (replaces the old standalone rmsnorm kernel)
  {
    float4 a = ((const float4*)sx)[2 * t], b = ((const float4*)sx)[2 * t + 1];
    short tmp[8];
    tmp[0] = f2bf(a.x * scale); tmp[1] = f2bf(a.y * scale);
    tmp[2] = f2bf(a.z * scale); tmp[3] = f2bf(a.w * scale);
    tmp[4] = f2bf(b.x * scale); tmp[5] = f2bf(b.y * scale);
    tmp[6] = f2bf(b.z * scale); tmp[7] = f2bf(b.w * scale);
    *(int4*)(xnb + (size_t)row * D_MODEL + t * 8) = *(int4*)tmp;
  }
  int h = t & 31, sl = t >> 5;
  float acc = 0.f;
  for (int k = sl * 256; k < sl * 256 + 256; k++)
    acc += sx[k] * w_in[(size_t)k * PROJ_DIM + (D_MODEL + CONV_DIMN) + h];
  red[sl][h] = acc;
  __syncthreads();
  if (t < 32) {
    float s = 0.f;
    #pragma unroll
    for (int i = 0; i < 8; i++) s += red[i][t];
    dtraw[(size_t)row * HEADS + t] = s * scale;
  }
}

// ---------------- pipelined MFMA GEMM: C[M,N] = A[M,K] @ BT[N,K]^T ---------
// Tile 256x128, BK=32, 4 waves (2Mx2N, per-wave 128x64 = 8x4 frags), 256
// threads. 3-buffer LDS rotation, prefetch dist 2, counted vmcnt (LPT=6,
// never 0 in main loop), raw s_barrier, setprio, XCD swizzle. 72 KiB LDS
// -> 2 blocks/CU.
//
// Geometry rationale (round-4): old per-wave tile was 128x32 (8x2 frags)
// = 10 ds_read_b128 per 16 MFMA (0.625 reads/MFMA) -> LDS-pipe-bound at
// MfmaUtil 32% (arith: 160 reads*~7cy vs 320cy MFMA per CU per K-iter).
// 128x64 per-wave (8x4) = 12 reads per 32 MFMA (0.375) -> 1.67x less LDS
// pressure. Same grids (576/256), same packing, same hazard structure.
template<bool BF16OUT>
__global__ __launch_bounds__(256, 2) void gemm_tw_k(const short* __restrict__ A,
                                                    const short* __restrict__ BT,
                                                    void* __restrict__ Cout,
                                                    int M, int N, int K) {
  constexpr int ABUF = 256 * 32;        // shorts per A buffer (16 KiB)
  constexpr int BUFS = ABUF + 128 * 32; // + B 128x32 shorts = 12288 shorts
  constexpr int LPT = 6;                // gld16 per tile per thread (A4 + B2)
  __shared__ short lds[3 * BUFS];       // 72 KiB

  const int t = threadIdx.x;
  const int lane = t & 63, w = t >> 6;  // 4 waves
  const int mr = lane & 15, q = lane >> 4;
  const int cq8 = (q ^ ((mr >> 1) & 3)) * 8;            // read k-chunk (swizzled)
  const int stj = ((lane & 3) ^ ((lane >> 3) & 3)) * 8; // stage global k-chunk
  const int str = lane >> 2;                            // stage row within 16
  const int wm = w & 1, wn = w >> 1;                    // 2M x 2N wave grid

  // bijective XCD swizzle (all grids here are %8==0)
  const int nbx = N >> 7;               // N/128
  const int nwg = nbx * (M >> 8);       // * M/256
  const int cpx = nwg >> 3;
  const int bid = blockIdx.x;
  const int swz = (bid & 7) * cpx + (bid >> 3);
  const int bx = swz % nbx, by = swz / nbx;
  const int m0 = by * 256, n0 = bx * 128;

  const int NT = K >> 5;   // assumes NT >= 3 (all call sites K=2048)
  f32x4 acc[8][4] = {};

  auto STAGE = [&](int tile, int buf) {
    short* dst = &lds[buf * BUFS];
    const int kb = tile * 32 + stj;
    #pragma unroll
    for (int cc = 0; cc < 4; cc++)
      gld16(A + (size_t)(m0 + w * 64 + cc * 16 + str) * K + kb,
            dst + (w * 64 + cc * 16) * 32);
    #pragma unroll
    for (int cc = 0; cc < 2; cc++)
      gld16(BT + (size_t)(n0 + w * 32 + cc * 16 + str) * K + kb,
            dst + ABUF + (w * 32 + cc * 16) * 32);
  };

  STAGE(0, 0); STAGE(1, 1);
  asm volatile("s_waitcnt vmcnt(%0)" :: "n"(LPT) : "memory");
  __builtin_amdgcn_s_barrier();

  int bufc = 0;
  for (int tt = 0; tt < NT; ++tt) {
    const short* sA = &lds[bufc * BUFS];
    const short* sB = sA + ABUF;
    if (tt + 2 < NT) STAGE(tt + 2, bufc >= 1 ? bufc - 1 : 2);
    short8 af[4], bfr[4];
    #pragma unroll
    for (int ni = 0; ni < 4; ni++)
      bfr[ni] = *(const short8*)&sB[(wn * 64 + ni * 16 + mr) * 32 + cq8];
    #pragma unroll
    for (int mi = 0; mi < 4; mi++)
      af[mi] = *(const short8*)&sA[(wm * 128 + mi * 16 + mr) * 32 + cq8];
    __builtin_amdgcn_s_setprio(1);
    #pragma unroll
    for (int mi = 0; mi < 4; mi++)
      #pragma unroll
      for (int ni = 0; ni < 4; ni++)
        acc[mi][ni] = __builtin_amdgcn_mfma_f32_16x16x32_bf16(af[mi], bfr[ni], acc[mi][ni], 0, 0, 0);
    __builtin_amdgcn_s_setprio(0);
    #pragma unroll
    for (int mi = 0; mi < 4; mi++)
      af[mi] = *(const short8*)&sA[(wm * 128 + 64 + mi * 16 + mr) * 32 + cq8];
    __builtin_amdgcn_s_setprio(1);
    #pragma unroll
    for (int mi = 0; mi < 4; mi++)
      #pragma unroll
      for (int ni = 0; ni < 4; ni++)
        acc[4 + mi][ni] = __builtin_amdgcn_mfma_f32_16x16x32_bf16(af[mi], bfr[ni], acc[4 + mi][ni], 0, 0, 0);
    __builtin_amdgcn_s_setprio(0);
    __builtin_amdgcn_sched_barrier(0);
    if (tt + 2 < NT) asm volatile("s_waitcnt vmcnt(%0)" :: "n"(LPT) : "memory");
    else             asm volatile("s_waitcnt vmcnt(0)" ::: "memory");
    __builtin_amdgcn_s_barrier();
    bufc = (bufc == 2) ? 0 : bufc + 1;
  }

  #pragma unroll
  for (int mi = 0; mi < 8; mi++)
    #pragma unroll
    for (int ni = 0; ni < 4; ni++) {
      const int gm = m0 + wm * 128 + ((mi & 3) + (mi >> 2) * 4) * 16 + ((mi >> 2) ? 64 - 64 : 0);
      // gm simplified below; keep straightforward:
      const int gmr = m0 + wm * 128 + (mi >> 2) * 64 + (mi & 3) * 16 + q * 4;
      const int gn = n0 + wn * 64 + ni * 16 + mr;
      #pragma unroll
      for (int r = 0; r < 4; r++) {
        if (BF16OUT) ((short*)Cout)[(size_t)(gmr + r) * N + gn] = f2bf(acc[mi][ni][r]);
        else         ((float*)Cout)[(size_t)(gmr + r) * N + gn] = acc[mi][ni][r];
      }
    }
}

// ------- depthwise causal conv + bias + SiLU, 8-channel vectorized ---------
__global__ __launch_bounds__(256) void conv_silu_k(const short* __restrict__ projb,
                                                   const float* __restrict__ cw,
                                                   const float* __restrict__ cb,
                                                   short* __restrict__ out) {
  int idx = blockIdx.x * 256 + threadIdx.x;   // BL * (CONV_DIM/8) total
  int ci = idx % (CONV_DIMN / 8);
  int bt = idx / (CONV_DIMN / 8);
  int t = bt & (SEQL - 1);
  int b = bt >> 11;
  int c = ci * 8;
  float4 w4[8];
  #pragma unroll
  for (int j = 0; j < 8; j++) w4[j] = ((const float4*)cw)[c + j];
  float acc[8];
  {
    float4 b0 = ((const float4*)(cb + c))[0], b1 = ((const float4*)(cb + c))[1];
    acc[0] = b0.x; acc[1] = b0.y; acc[2] = b0.z; acc[3] = b0.w;
    acc[4] = b1.x; acc[5] = b1.y; acc[6] = b1.z; acc[7] = b1.w;
  }
  #pragma unroll
  for (int k = 0; k < KCONV; k++) {
    int tt = t - (KCONV - 1) + k;
    if (tt < 0) continue;
    short8 v = *(const short8*)&projb[((size_t)(b * SEQL + tt)) * PROJB_W + D_MODEL + c];
    #pragma unroll
    for (int j = 0; j < 8; j++) {
      float wv = (k == 0) ? w4[j].x : (k == 1) ? w4[j].y : (k == 2) ? w4[j].z : w4[j].w;
      acc[j] += b2f(v[j]) * wv;
    }
  }
  short o[8];
  #pragma unroll
  for (int j = 0; j < 8; j++) o[j] = f2bf(acc[j] / (1.f + expf(-acc[j])));
  *(int4*)&out[(size_t)bt * CONV_DIMN + c] = *(int4*)o;
}

// ---------------- dt softplus + per-chunk cumsum of A*dt (4 waves) ---------
__global__ __launch_bounds__(256) void dt_acs_k(const float* __restrict__ dtraw,
                                                const float* __restrict__ dt_bias,
                                                const float* __restrict__ A_log,
                                                float* __restrict__ dtb, float* __restrict__ acsb) {
  int bc = blockIdx.x;
  int b = bc / NC, c = bc % NC;
  int t = threadIdx.x;
  int l = t & 63, w = t >> 6;     // wave w handles heads w*8..w*8+7
  size_t base = ((size_t)(b * SEQL + c * CHUNK + l)) * HEADS;
  #pragma unroll
  for (int i = 0; i < 8; i++) {
    int h = w * 8 + i;
    float raw = dtraw[base + h] + dt_bias[h];
    float dt = raw > 20.f ? raw : log1pf(expf(raw));
    float adt = -expf(A_log[h]) * dt;
    float cs = adt;
    #pragma unroll
    for (int off = 1; off < 64; off <<= 1) {
      float v = __shfl_up(cs, off);
      if (l >= off) cs += v;
    }
    dtb[base + h] = dt;
    acsb[base + h] = cs;
  }
}

// ---------------- CB[b,c,l,s] = sum_n C(l,n)*B(s,n) -> bf16 ----------------
__global__ __launch_bounds__(256) void cb_k(const short* __restrict__ convb,
                                            short* __restrict__ CB) {
  int bc = blockIdx.x;
  int b = bc / NC, c = bc % NC;
  __shared__ float sC[64][65];
  __shared__ float sB[64][65];
  int t = threadIdx.x;
  int s = t & 63;
  int lb = (t >> 6) * 16;
  float acc[16] = {};
  size_t rowb = ((size_t)(b * SEQL + c * CHUNK)) * CONV_DIMN;
  for (int nt = 0; nt < 4; nt++) {
    __syncthreads();
    #pragma unroll
    for (int i = 0; i < 16; i++) {
      int e = t + 256 * i;
      int r = e >> 6, col = e & 63;
      sC[r][col] = b2f(convb[rowb + (size_t)r * CONV_DIMN + (D_MODEL + STATE) + nt * 64 + col]);
      sB[r][col] = b2f(convb[rowb + (size_t)r * CONV_DIMN + D_MODEL + nt * 64 + col]);
    }
    __syncthreads();
    for (int n = 0; n < 64; n++) {
      float bv = sB[s][n];
      #pragma unroll
      for (int j = 0; j < 16; j++) acc[j] += sC[lb + j][n] * bv;
    }
  }
  size_t ob = ((size_t)bc) * 64 * 64;
  #pragma unroll
  for (int j = 0; j < 16; j++) CB[ob + (size_t)(lb + j) * 64 + s] = f2bf(acc[j]);
}

// ------- chunk states via MFMA, BOTH batches in one launch (grid 2048) -----
__global__ __launch_bounds__(256) void chunk_states_k(const short* __restrict__ convb,
                                                      const float* __restrict__ dtb,
                                                      const float* __restrict__ acsb,
                                                      short* __restrict__ G0,
                                                      short* __restrict__ G1) {
  int blk = blockIdx.x & 1023;     // c*HEADS + h
  int b = blockIdx.x >> 10;
  short* G = b ? G1 : G0;
  int h = blk & 31, c = blk >> 5;
  __shared__ __align__(16) short sXT[64][72];   // [p][l-swz] = bf16(xs(l,p)*wt(l))
  __shared__ __align__(16) short sBT[256][72];  // [n][l-swz] = B(l,n)
  __shared__ float swt[64];
  int t = threadIdx.x;
  size_t rowb = ((size_t)(b * SEQL + c * CHUNK)) * CONV_DIMN;
  size_t ab = ((size_t)(b * SEQL + c * CHUNK)) * HEADS;
  if (t < 64) {
    float a = acsb[ab + (size_t)t * HEADS + h];
    float alast = acsb[ab + (size_t)63 * HEADS + h];
    swt[t] = expf(alast - a) * dtb[ab + (size_t)t * HEADS + h];
  }
  __syncthreads();
  #pragma unroll
  for (int i = 0; i < 4; i++) {
    int e = t + 256 * i;
    int l = e >> 4, p4 = (e & 15) * 4;
    short4v v = *(const short4v*)&convb[rowb + (size_t)l * CONV_DIMN + h * HEAD_DIM + p4];
    float wt = swt[l];
    short vv[4] = {v.x, v.y, v.z, v.w};
    #pragma unroll
    for (int j = 0; j < 4; j++) {
      int p = p4 + j;
      sXT[p][((((l >> 3) ^ ((p >> 2) & 7)) << 3) | (l & 7))] = f2bf(b2f(vv[j]) * wt);
    }
  }
  #pragma unroll
  for (int i = 0; i < 16; i++) {
    int e = t + 256 * i;
    int l = e >> 6, n4 = (e & 63) * 4;
    short4v v = *(const short4v*)&convb[rowb + (size_t)l * CONV_DIMN + D_MODEL + n4];
    short vv[4] = {v.x, v.y, v.z, v.w};
    #pragma unroll
    for (int j = 0; j < 4; j++) {
      int n = n4 + j;
      sBT[n][((((l >> 3) ^ ((n >> 2) & 7)) << 3) | (l & 7))] = vv[j];
    }
  }
  __syncthreads();
  int lane = t & 63, w = t >> 6;
  int mr = lane & 15, q = lane >> 4;
  f32x4 acc[4][4] = {};
  #pragma unroll
  for (int ks = 0; ks < 2; ks++) {
    short8 af[4], bfr[4];
    #pragma unroll
    for (int mi = 0; mi < 4; mi++) {
      int p = mi * 16 + mr;
      af[mi] = *(const short8*)&sXT[p][(((ks * 4 + q) ^ ((p >> 2) & 7)) << 3)];
    }
    #pragma unroll
    for (int ni = 0; ni < 4; ni++) {
      int n = w * 64 + ni * 16 + mr;
      bfr[ni] = *(const short8*)&sBT[n][(((ks * 4 + q) ^ ((n >> 2) & 7)) << 3)];
    }
    #pragma unroll
    for (int mi = 0; mi < 4; mi++)
      #pragma unroll
      for (int ni = 0; ni < 4; ni++)
        acc[mi][ni] = __builtin_amdgcn_mfma_f32_16x16x32_bf16(af[mi], bfr[ni], acc[mi][ni], 0, 0, 0);
  }
  size_t gb = (size_t)blk * (64 * 256);
  #pragma unroll
  for (int mi = 0; mi < 4; mi++)
    #pragma unroll
    for (int ni = 0; ni < 4; ni++)
      #pragma unroll
      for (int r = 0; r < 4; r++)
        G[gb + (size_t)(mi * 16 + q * 4 + r) * 256 + w * 64 + ni * 16 + mr] = f2bf(acc[mi][ni][r]);
}

// ------- sequential chunk recursion, both batches, int4-vectorized ---------
__global__ __launch_bounds__(256) void scan_states_k(short* __restrict__ G0,
                                                     short* __restrict__ G1,
                                                     const float* __restrict__ acsb) {
  int gid = blockIdx.x * 256 + threadIdx.x;   // 512 blocks = 131072 threads
  int b = gid >> 16;
  int tid = gid & 65535;                       // 65536 threads per batch
  short* G = b ? G1 : G0;
  int n8 = tid & 31, p = (tid >> 5) & 63, h = tid >> 11;
  float S[8] = {};
  for (int c = 0; c < NC; c++) {
    size_t base = (((size_t)(c * HEADS + h) * 64) + p) * 256 + n8 * 8;
    short gs[8];
    *(int4*)gs = *(const int4*)&G[base];
    short ws8[8];
    #pragma unroll
    for (int j = 0; j < 8; j++) ws8[j] = f2bf(S[j]);
    *(int4*)&G[base] = *(int4*)ws8;
    float dec = expf(acsb[((size_t)(b * SEQL + c * CHUNK + 63)) * HEADS + h]);
    #pragma unroll
    for (int j = 0; j < 8; j++) S[j] = S[j] * dec + b2f(gs[j]);
  }
}

// ------- fused Y = Ydiag + ea_l*Yoff + D*xs, BOTH batches (grid 2048) ------
__global__ __launch_bounds__(256) void y_fused_k(const short* __restrict__ convb,
                                                 const short* __restrict__ CBb,
                                                 const short* __restrict__ G0,
                                                 const short* __restrict__ G1,
                                                 const float* __restrict__ dtb,
                                                 const float* __restrict__ acsb,
                                                 const float* __restrict__ D_skip,
                                                 float* __restrict__ Y) {
  int blk = blockIdx.x & 1023;     // c*HEADS + h
  int b = blockIdx.x >> 10;
  const short* G = b ? G1 : G0;
  int h = blk & 31, c = blk >> 5;
  __shared__ __align__(16) short sM[64][72];    // M(l,s) bf16, plain cols
  __shared__ __align__(16) short sXT[64][72];   // [p][l-swz] = xs(l,p)
  __shared__ float sacs[64], sdt[64], sea[64];
  int t = threadIdx.x;
  int lane = t & 63, w = t >> 6;
  size_t rowb = ((size_t)(b * SEQL + c * CHUNK)) * CONV_DIMN;
  size_t ab = ((size_t)(b * SEQL + c * CHUNK)) * HEADS;
  size_t cbbase = ((size_t)(b * NC + c)) * 64 * 64;
  if (t < 64) {
    float a = acsb[ab + (size_t)t * HEADS + h];
    sacs[t] = a;
    sea[t] = expf(a);
    sdt[t] = dtb[ab + (size_t)t * HEADS + h];
  }
  __syncthreads();
  // stage M(l,s) = CB * exp(acs_l - acs_s) * dt_s * [s<=l]
  #pragma unroll
  for (int i = 0; i < 16; i++) {
    int e = t + 256 * i;
    int r = e >> 6, col = e & 63;
    float m = 0.f;
    if (col <= r)
      m = b2f(CBb[cbbase + (size_t)r * 64 + col]) * expf(sacs[r] - sacs[col]) * sdt[col];
    sM[r][col] = f2bf(m);
  }
  // stage xs^T (raw)
  #pragma unroll
  for (int i = 0; i < 4; i++) {
    int e = t + 256 * i;
    int l = e >> 4, p4 = (e & 15) * 4;
    short4v v = *(const short4v*)&convb[rowb + (size_t)l * CONV_DIMN + h * HEAD_DIM + p4];
    short vv[4] = {v.x, v.y, v.z, v.w};
    #pragma unroll
    for (int j = 0; j < 4; j++) {
      int p = p4 + j;
      sXT[p][((((l >> 3) ^ ((p >> 2) & 7)) << 3) | (l & 7))] = vv[j];
    }
  }
  __syncthreads();
  int mr = lane & 15, q = lane >> 4;
  int wm = (w & 1) * 32, wn = (w >> 1) * 32;
  f32x4 acc1[2][2] = {}, acc2[2][2] = {};
  // MFMA1: Ydiag
  #pragma unroll
  for (int ks = 0; ks < 2; ks++) {
    short8 af[2], bfr[2];
    #pragma unroll
    for (int mi = 0; mi < 2; mi++)
      af[mi] = *(const short8*)&sM[wm + mi * 16 + mr][ks * 32 + q * 8];
    #pragma unroll
    for (int ni = 0; ni < 2; ni++) {
      int p = wn + ni * 16 + mr;
      bfr[ni] = *(const short8*)&sXT[p][(((ks * 4 + q) ^ ((p >> 2) & 7)) << 3)];
    }
    #pragma unroll
    for (int mi = 0; mi < 2; mi++)
      #pragma unroll
      for (int ni = 0; ni < 2; ni++)
        acc1[mi][ni] = __builtin_amdgcn_mfma_f32_16x16x32_bf16(af[mi], bfr[ni], acc1[mi][ni], 0, 0, 0);
  }
  // MFMA2: Yoff/ea -- operands direct from global (raw C rows, S rows)
  const short* Crow = convb + rowb + (D_MODEL + STATE);
  size_t gbase = (size_t)blk * (64 * 256);
  #pragma unroll
  for (int st = 0; st < 8; st++) {
    short8 af[2], bfr[2];
    #pragma unroll
    for (int mi = 0; mi < 2; mi++) {
      int l = wm + mi * 16 + mr;
      af[mi] = *(const short8*)&Crow[(size_t)l * CONV_DIMN + st * 32 + q * 8];
    }
    #pragma unroll
    for (int ni = 0; ni < 2; ni++) {
      int p = wn + ni * 16 + mr;
      bfr[ni] = *(const short8*)&G[gbase + (size_t)p * 256 + st * 32 + q * 8];
    }
    #pragma unroll
    for (int mi = 0; mi < 2; mi++)
      #pragma unroll
      for (int ni = 0; ni < 2; ni++)
        acc2[mi][ni] = __builtin_amdgcn_mfma_f32_16x16x32_bf16(af[mi], bfr[ni], acc2[mi][ni], 0, 0, 0);
  }
  // epilogue
  float dsk = D_skip[h];
  size_t ybase = ((size_t)(b * SEQL + c * CHUNK)) * D_MODEL + h * HEAD_DIM;
  #pragma unroll
  for (int mi = 0; mi < 2; mi++)
    #pragma unroll
    for (int ni = 0; ni < 2; ni++) {
      int p = wn + ni * 16 + mr;
      #pragma unroll
      for (int r = 0; r < 4; r++) {
        int l = wm + mi * 16 + q * 4 + r;
        float xsv = b2f(sXT[p][((((l >> 3) ^ ((p >> 2) & 7)) << 3) | (l & 7))]);
        Y[ybase + (size_t)l * D_MODEL + p] =
            acc1[mi][ni][r] + sea[l] * acc2[mi][ni][r] + dsk * xsv;
      }
    }
}

// ---------------- gated RMSNorm -> bf16 (z from projb) ---------------------
__global__ __launch_bounds__(256) void gated_norm_bf16_k(const float* __restrict__ Y,
                                                         const short* __restrict__ projb,
                                                         const float* __restrict__ gw,
                                                         short* __restrict__ out) {
  int row = blockIdx.x;
  int t = threadIdx.x;
  const float4* y4 = (const float4*)(Y + (size_t)row * D_MODEL);
  float4 ya = y4[2 * t], yb = y4[2 * t + 1];
  short zt[8];
  *(int4*)zt = *(const int4*)(projb + (size_t)row * PROJB_W + t * 8);
  float g[8];
  float yv[8] = {ya.x, ya.y, ya.z, ya.w, yb.x, yb.y, yb.z, yb.w};
  float ss = 0.f;
  #pragma unroll
  for (int i = 0; i < 8; i++) {
    float z = b2f(zt[i]);
    g[i] = yv[i] * (z / (1.f + expf(-z)));
    ss += g[i] * g[i];
  }
  #pragma unroll
  for (int off = 32; off > 0; off >>= 1) ss += __shfl_down(ss, off);
  __shared__ float ws_[4];
  if ((t & 63) == 0) ws_[t >> 6] = ss;
  __syncthreads();
  float tot = ws_[0] + ws_[1] + ws_[2] + ws_[3];
  float scale = rsqrtf(tot / (float)D_MODEL + EPSF);
  const float4* g4 = (const float4*)gw;
  float4 wa = g4[2 * t], wb = g4[2 * t + 1];
  float wv[8] = {wa.x, wa.y, wa.z, wa.w, wb.x, wb.y, wb.z, wb.w};
  short tmp[8];
  #pragma unroll
  for (int i = 0; i < 8; i++) tmp[i] = f2bf(g[i] * scale * wv[i]);
  *(int4*)(out + (size_t)row * D_MODEL + t * 8) = *(int4*)tmp;
}

extern "C" void kernel_launch(void* const* d_in, const int* in_sizes, int n_in,
                              void* d_out, int out_size, void* d_ws, size_t ws_size,
                              hipStream_t stream) {
  const float* x       = (const float*)d_in[0];
  const float* norm_w  = (const float*)d_in[1];
  const float* w_in    = (const float*)d_in[2];
  const float* conv_w  = (const float*)d_in[3];
  const float* conv_b  = (const float*)d_in[4];
  const float* dt_bias = (const float*)d_in[5];
  const float* A_log   = (const float*)d_in[6];
  const float* D_skip  = (const float*)d_in[7];
  const float* gnorm_w = (const float*)d_in[8];
  const float* w_out   = (const float*)d_in[9];
  const float* wo_w    = (const float*)d_in[10];
  float* out = (float*)d_out;

  // workspace (float units), total 36,700,160 fu = 140 MiB
  float* ws    = (float*)d_ws;
  short* xnb   = (short*)ws;                 // [0 .. 4,194,304 fu)  bf16 4096x2048
  short* w_inT = (short*)(ws + 4194304);     // 4,718,592 fu         bf16 4608x2048
  short* projb = (short*)(ws + 8912896);     // 9,437,184 fu         bf16 4096x4608
  short* convb = (short*)(ws + 18350080);    // 5,242,880 fu         bf16 4096x2560
  float* dtraw = ws + 23592960;              // 131,072
  float* dtb   = ws + 23724032;              // 131,072
  float* acsb  = ws + 23855104;              // 131,072
  short* CBb   = (short*)(ws + 23986176);    // 131,072 fu           bf16 64x64x64
  float* Yb    = ws + 24117248;              // 8,388,608
  short* w_outT= (short*)(ws + 32505856);    // 2,097,152 fu
  short* wo_wT = (short*)(ws + 34603008);    // 2,097,152 fu
  short* G0    = (short*)ws;                 // batch-0 states: 33.5 MB over xnb+w_inT (dead after big GEMM)
  short* G1    = (short*)out;                // batch-1 states: d_out (33.5 MB) is dead until final GEMM
  short* Yg    = convb;                      // overlays convb after y_fused
  short* t1b   = (short*)ws;                 // overlays G0 region after y_fused

  dt_gemm_k<<<BL, 256, 0, stream>>>(x, norm_w, w_in, xnb, dtraw);
  transpose_bf16_k<<<dim3(PROJB_W / 32, D_MODEL / 32), 256, 0, stream>>>(w_in, w_inT, D_MODEL, PROJB_W, PROJ_DIM);
  transpose_bf16_k<<<dim3(D_MODEL / 32, D_MODEL / 32), 256, 0, stream>>>(w_out, w_outT, D_MODEL, D_MODEL, D_MODEL);
  transpose_bf16_k<<<dim3(D_MODEL / 32, D_MODEL / 32), 256, 0, stream>>>(wo_w, wo_wT, D_MODEL, D_MODEL, D_MODEL);
  gemm_tw_k<true><<<(BL / 256) * (PROJB_W / 128), 256, 0, stream>>>(xnb, w_inT, projb, BL, PROJB_W, D_MODEL);
  conv_silu_k<<<(BL * (CONV_DIMN / 8)) / 256, 256, 0, stream>>>(projb, conv_w, conv_b, convb);
  dt_acs_k<<<BATCHN * NC, 256, 0, stream>>>(dtraw, dt_bias, A_log, dtb, acsb);
  cb_k<<<BATCHN * NC, 256, 0, stream>>>(convb, CBb);
  chunk_states_k<<<BATCHN * NC * HEADS, 256, 0, stream>>>(convb, dtb, acsb, G0, G1);
  scan_states_k<<<512, 256, 0, stream>>>(G0, G1, acsb);
  y_fused_k<<<BATCHN * NC * HEADS, 256, 0, stream>>>(convb, CBb, G0, G1, dtb, acsb, D_skip, Yb);
  gated_norm_bf16_k<<<BL, 256, 0, stream>>>(Yb, projb, gnorm_w, Yg);
  gemm_tw_k<true><<<(BL / 256) * (D_MODEL / 128), 256, 0, stream>>>(Yg, w_outT, t1b, BL, D_MODEL, D_MODEL);
  gemm_tw_k<false><<<(BL / 256) * (D_MODEL / 128), 256, 0, stream>>>(t1b, wo_wT, out, BL, D_MODEL, D_MODEL);
}

// Round 5
// 605.512 us; speedup vs baseline: 1.0015x; 1.0015x over previous
//
#include <hip/hip_runtime.h>
#include <math.h>

#define D_MODEL 2048
#define HEADS 32
#define HEAD_DIM 64
#define STATE 256
#define KCONV 4
#define CHUNK 64
#define NC 32            // SEQ / CHUNK
#define SEQL 2048
#define BATCHN 2
#define CONV_DIMN 2560   // D_MODEL + 2*STATE
#define PROJ_DIM 4640    // D_MODEL + CONV_DIM + HEADS
#define PROJB_W 4608     // 36*128: z + xBC cols (dt handled by dt_gemm)
#define EPSF 1e-5f
#define BL (BATCHN * SEQL)  // 4096 token rows

typedef __attribute__((ext_vector_type(8))) short short8;
typedef __attribute__((ext_vector_type(4))) short short4v;
typedef __attribute__((ext_vector_type(4))) float f32x4;

__device__ __forceinline__ short f2bf(float f) {
  unsigned u = __builtin_bit_cast(unsigned, f);
  u = (u + 0x7fffu + ((u >> 16) & 1u)) >> 16;   // RNE
  return (short)u;
}
__device__ __forceinline__ float b2f(short s) {
  unsigned u = ((unsigned)(unsigned short)s) << 16;
  return __builtin_bit_cast(float, u);
}
__device__ __forceinline__ void gld16(const void* g, void* l) {
  __builtin_amdgcn_global_load_lds((const __attribute__((address_space(1))) unsigned int*)g,
                                   (__attribute__((address_space(3))) unsigned int*)l,
                                   16, 0, 0);
}

// ---------------- transpose + fp32->bf16 -----------------------------------
__global__ __launch_bounds__(256) void transpose_bf16_k(const float* __restrict__ W,
                                                        short* __restrict__ WT,
                                                        int K, int ncols, int stride) {
  __shared__ float tile[32][33];
  int bn = blockIdx.x * 32, bk = blockIdx.y * 32;
  int tx = threadIdx.x & 31, ty = threadIdx.x >> 5;  // ty 0..7
  #pragma unroll
  for (int i = 0; i < 32; i += 8) {
    int k = bk + ty + i, n = bn + tx;
    tile[ty + i][tx] = (n < ncols) ? W[(size_t)k * stride + n] : 0.f;
  }
  __syncthreads();
  #pragma unroll
  for (int i = 0; i < 32; i += 8) {
    int n = bn + ty + i, k = bk + tx;
    WT[(size_t)n * K + k] = f2bf(tile[tx][ty + i]);
  }
}

// ------- fused RMSNorm: writes xnb (bf16 normalized row) + dtraw -----------
__global__ __launch_bounds__(256) void dt_gemm_k(const float* __restrict__ x,
                                                 const float* __restrict__ norm_w,
                                                 const float* __restrict__ w_in,
                                                 short* __restrict__ xnb,
                                                 float* __restrict__ dtraw) {
  int row = blockIdx.x;
  int t = threadIdx.x;
  __shared__ float sx[D_MODEL];
  __shared__ float red[8][32];
  __shared__ float sred[4];
  const float4* x4 = (const float4*)(x + (size_t)row * D_MODEL);
  const float4* nw4 = (const float4*)norm_w;
  float ss = 0.f;
  for (int i = t; i < D_MODEL / 4; i += 256) {
    float4 v = x4[i];
    ss += v.x * v.x + v.y * v.y + v.z * v.z + v.w * v.w;
    float4 nw = nw4[i];
    float4 pv; pv.x = v.x * nw.x; pv.y = v.y * nw.y; pv.z = v.z * nw.z; pv.w = v.w * nw.w;
    ((float4*)sx)[i] = pv;
  }
  #pragma unroll
  for (int off = 32; off > 0; off >>= 1) ss += __shfl_down(ss, off);
  if ((t & 63) == 0) sred[t >> 6] = ss;
  __syncthreads();
  float tot = sred[0] + sred[1] + sred[2] + sred[3];
  float scale = rsqrtf(tot / (float)D_MODEL + EPSF);
  // write normalized bf16 row (replaces the old standalone rmsnorm kernel)
  {
    float4 a = ((const float4*)sx)[2 * t], b = ((const float4*)sx)[2 * t + 1];
    short tmp[8];
    tmp[0] = f2bf(a.x * scale); tmp[1] = f2bf(a.y * scale);
    tmp[2] = f2bf(a.z * scale); tmp[3] = f2bf(a.w * scale);
    tmp[4] = f2bf(b.x * scale); tmp[5] = f2bf(b.y * scale);
    tmp[6] = f2bf(b.z * scale); tmp[7] = f2bf(b.w * scale);
    *(int4*)(xnb + (size_t)row * D_MODEL + t * 8) = *(int4*)tmp;
  }
  int h = t & 31, sl = t >> 5;
  float acc = 0.f;
  for (int k = sl * 256; k < sl * 256 + 256; k++)
    acc += sx[k] * w_in[(size_t)k * PROJ_DIM + (D_MODEL + CONV_DIMN) + h];
  red[sl][h] = acc;
  __syncthreads();
  if (t < 32) {
    float s = 0.f;
    #pragma unroll
    for (int i = 0; i < 8; i++) s += red[i][t];
    dtraw[(size_t)row * HEADS + t] = s * scale;
  }
}

// ------- phase-split pipelined MFMA GEMM: C[M,N] = A[M,K] @ BT[N,K]^T ------
// Tile 256x128, BK=64 (two 32-k halves, each laid out exactly like the
// proven BK=32 buffers incl. XOR swizzle), 8 waves (4Mx2N, per-wave 64x64
// = 4x4 frags), 3-buffer rotation w/ prefetch dist 2, counted vmcnt(6)
// once per K-tile (never 0 in main loop), and per K-tile TWO lockstep
// phases: {ds_read frags || issue stage(t+2) -> s_barrier -> lgkmcnt(0)
// -> setprio(1) 16 MFMA -> s_barrier}.  LDS 144 KiB -> 1 block/CU.
//
// The intra-tile barriers are performance-only (wave convoy so MFMA
// clusters coincide and loads fly under them).  Correctness hazards are
// closed exactly as in the previously-verified kernel: WAR - stage(t+2)
// writes buf(t-1), whose reads all retired before tile-(t-1)'s closing
// barrier; RAW - each wave's vmcnt(6) retires its own tile-(t+1) loads,
// the following barrier makes that global.
template<bool BF16OUT>
__global__ __launch_bounds__(512, 1) void gemm8p_k(const short* __restrict__ A,
                                                   const short* __restrict__ BT,
                                                   void* __restrict__ Cout,
                                                   int M, int N, int K) {
  constexpr int AHALF = 8192;               // 256x32 shorts (16 KiB)
  constexpr int BHALF = 4096;               // 128x32 shorts (8 KiB)
  constexpr int ATILE = 2 * AHALF;          // 16384 shorts
  constexpr int BUFS  = ATILE + 2 * BHALF;  // 24576 shorts (48 KiB)
  __shared__ short lds[3 * BUFS];           // 144 KiB

  const int t = threadIdx.x;
  const int lane = t & 63, w = t >> 6;      // 8 waves
  const int mr = lane & 15, q = lane >> 4;
  const int cq8 = (q ^ ((mr >> 1) & 3)) * 8;            // read k-chunk (swizzled)
  const int stj = ((lane & 3) ^ ((lane >> 3) & 3)) * 8; // stage global k-chunk
  const int str = lane >> 2;                            // stage row within 16
  const int wm = w & 3, wn = w >> 2;                    // 4M x 2N wave grid

  // bijective XCD swizzle (all grids here are %8==0)
  const int nbx = N >> 7;               // N/128
  const int nwg = nbx * (M >> 8);       // * M/256
  const int cpx = nwg >> 3;
  const int bid = blockIdx.x;
  const int swz = (bid & 7) * cpx + (bid >> 3);
  const int bx = swz % nbx, by = swz / nbx;
  const int m0 = by * 256, n0 = bx * 128;

  const int NT = K >> 6;   // K=2048 -> 32 tiles of 64
  f32x4 acc[4][4] = {};

  auto STAGE_A = [&](int tile, int buf) {
    short* dst = &lds[buf * BUFS];
    #pragma unroll
    for (int s = 0; s < 2; s++) {
      const int kb = tile * 64 + s * 32 + stj;
      #pragma unroll
      for (int cc = 0; cc < 2; cc++)
        gld16(A + (size_t)(m0 + w * 32 + cc * 16 + str) * K + kb,
              dst + s * AHALF + (w * 32 + cc * 16) * 32);
    }
  };
  auto STAGE_B = [&](int tile, int buf) {
    short* dst = &lds[buf * BUFS + ATILE];
    #pragma unroll
    for (int s = 0; s < 2; s++) {
      const int kb = tile * 64 + s * 32 + stj;
      gld16(BT + (size_t)(n0 + w * 16 + str) * K + kb,
            dst + s * BHALF + w * 512);
    }
  };

  STAGE_A(0, 0); STAGE_B(0, 0);        // 6 loads / thread
  STAGE_A(1, 1); STAGE_B(1, 1);        // +6 -> 12 outstanding
  asm volatile("s_waitcnt vmcnt(6)" ::: "memory");   // tile 0 resident
  __builtin_amdgcn_s_barrier();

  int bufc = 0;
  for (int tt = 0; tt < NT; ++tt) {
    const int pb = bufc >= 1 ? bufc - 1 : 2;          // buf of tile t+2 (== t-1)
    const short* sAb = &lds[bufc * BUFS];
    const short* sBb = sAb + ATILE;
    const bool pf = (tt + 2 < NT);
    #pragma unroll
    for (int s = 0; s < 2; s++) {
      const short* sA = sAb + s * AHALF;
      const short* sB = sBb + s * BHALF;
      short8 af[4], bfr[4];
      #pragma unroll
      for (int mi = 0; mi < 4; mi++)
        af[mi] = *(const short8*)&sA[(wm * 64 + mi * 16 + mr) * 32 + cq8];
      #pragma unroll
      for (int ni = 0; ni < 4; ni++)
        bfr[ni] = *(const short8*)&sB[(wn * 64 + ni * 16 + mr) * 32 + cq8];
      if (pf) { if (s == 0) STAGE_A(tt + 2, pb); else STAGE_B(tt + 2, pb); }
      __builtin_amdgcn_s_barrier();
      asm volatile("s_waitcnt lgkmcnt(0)" ::: "memory");
      __builtin_amdgcn_sched_barrier(0);
      __builtin_amdgcn_s_setprio(1);
      #pragma unroll
      for (int mi = 0; mi < 4; mi++)
        #pragma unroll
        for (int ni = 0; ni < 4; ni++)
          acc[mi][ni] = __builtin_amdgcn_mfma_f32_16x16x32_bf16(af[mi], bfr[ni], acc[mi][ni], 0, 0, 0);
      __builtin_amdgcn_s_setprio(0);
      __builtin_amdgcn_sched_barrier(0);
      if (s == 0) {
        __builtin_amdgcn_s_barrier();
      } else {
        if (pf) asm volatile("s_waitcnt vmcnt(6)" ::: "memory");
        else    asm volatile("s_waitcnt vmcnt(0)" ::: "memory");
        __builtin_amdgcn_s_barrier();
      }
    }
    bufc = (bufc == 2) ? 0 : bufc + 1;
  }

  #pragma unroll
  for (int mi = 0; mi < 4; mi++)
    #pragma unroll
    for (int ni = 0; ni < 4; ni++) {
      const int gm = m0 + wm * 64 + mi * 16 + q * 4;
      const int gn = n0 + wn * 64 + ni * 16 + mr;
      #pragma unroll
      for (int r = 0; r < 4; r++) {
        if (BF16OUT) ((short*)Cout)[(size_t)(gm + r) * N + gn] = f2bf(acc[mi][ni][r]);
        else         ((float*)Cout)[(size_t)(gm + r) * N + gn] = acc[mi][ni][r];
      }
    }
}

// ------- depthwise causal conv + bias + SiLU, 8-channel vectorized ---------
__global__ __launch_bounds__(256) void conv_silu_k(const short* __restrict__ projb,
                                                   const float* __restrict__ cw,
                                                   const float* __restrict__ cb,
                                                   short* __restrict__ out) {
  int idx = blockIdx.x * 256 + threadIdx.x;   // BL * (CONV_DIM/8) total
  int ci = idx % (CONV_DIMN / 8);
  int bt = idx / (CONV_DIMN / 8);
  int t = bt & (SEQL - 1);
  int b = bt >> 11;
  int c = ci * 8;
  float4 w4[8];
  #pragma unroll
  for (int j = 0; j < 8; j++) w4[j] = ((const float4*)cw)[c + j];
  float acc[8];
  {
    float4 b0 = ((const float4*)(cb + c))[0], b1 = ((const float4*)(cb + c))[1];
    acc[0] = b0.x; acc[1] = b0.y; acc[2] = b0.z; acc[3] = b0.w;
    acc[4] = b1.x; acc[5] = b1.y; acc[6] = b1.z; acc[7] = b1.w;
  }
  #pragma unroll
  for (int k = 0; k < KCONV; k++) {
    int tt = t - (KCONV - 1) + k;
    if (tt < 0) continue;
    short8 v = *(const short8*)&projb[((size_t)(b * SEQL + tt)) * PROJB_W + D_MODEL + c];
    #pragma unroll
    for (int j = 0; j < 8; j++) {
      float wv = (k == 0) ? w4[j].x : (k == 1) ? w4[j].y : (k == 2) ? w4[j].z : w4[j].w;
      acc[j] += b2f(v[j]) * wv;
    }
  }
  short o[8];
  #pragma unroll
  for (int j = 0; j < 8; j++) o[j] = f2bf(acc[j] / (1.f + expf(-acc[j])));
  *(int4*)&out[(size_t)bt * CONV_DIMN + c] = *(int4*)o;
}

// ---------------- dt softplus + per-chunk cumsum of A*dt (4 waves) ---------
__global__ __launch_bounds__(256) void dt_acs_k(const float* __restrict__ dtraw,
                                                const float* __restrict__ dt_bias,
                                                const float* __restrict__ A_log,
                                                float* __restrict__ dtb, float* __restrict__ acsb) {
  int bc = blockIdx.x;
  int b = bc / NC, c = bc % NC;
  int t = threadIdx.x;
  int l = t & 63, w = t >> 6;     // wave w handles heads w*8..w*8+7
  size_t base = ((size_t)(b * SEQL + c * CHUNK + l)) * HEADS;
  #pragma unroll
  for (int i = 0; i < 8; i++) {
    int h = w * 8 + i;
    float raw = dtraw[base + h] + dt_bias[h];
    float dt = raw > 20.f ? raw : log1pf(expf(raw));
    float adt = -expf(A_log[h]) * dt;
    float cs = adt;
    #pragma unroll
    for (int off = 1; off < 64; off <<= 1) {
      float v = __shfl_up(cs, off);
      if (l >= off) cs += v;
    }
    dtb[base + h] = dt;
    acsb[base + h] = cs;
  }
}

// ---------------- CB[b,c,l,s] = sum_n C(l,n)*B(s,n) -> bf16 ----------------
__global__ __launch_bounds__(256) void cb_k(const short* __restrict__ convb,
                                            short* __restrict__ CB) {
  int bc = blockIdx.x;
  int b = bc / NC, c = bc % NC;
  __shared__ float sC[64][65];
  __shared__ float sB[64][65];
  int t = threadIdx.x;
  int s = t & 63;
  int lb = (t >> 6) * 16;
  float acc[16] = {};
  size_t rowb = ((size_t)(b * SEQL + c * CHUNK)) * CONV_DIMN;
  for (int nt = 0; nt < 4; nt++) {
    __syncthreads();
    #pragma unroll
    for (int i = 0; i < 16; i++) {
      int e = t + 256 * i;
      int r = e >> 6, col = e & 63;
      sC[r][col] = b2f(convb[rowb + (size_t)r * CONV_DIMN + (D_MODEL + STATE) + nt * 64 + col]);
      sB[r][col] = b2f(convb[rowb + (size_t)r * CONV_DIMN + D_MODEL + nt * 64 + col]);
    }
    __syncthreads();
    for (int n = 0; n < 64; n++) {
      float bv = sB[s][n];
      #pragma unroll
      for (int j = 0; j < 16; j++) acc[j] += sC[lb + j][n] * bv;
    }
  }
  size_t ob = ((size_t)bc) * 64 * 64;
  #pragma unroll
  for (int j = 0; j < 16; j++) CB[ob + (size_t)(lb + j) * 64 + s] = f2bf(acc[j]);
}

// ------- chunk states via MFMA, BOTH batches in one launch (grid 2048) -----
__global__ __launch_bounds__(256) void chunk_states_k(const short* __restrict__ convb,
                                                      const float* __restrict__ dtb,
                                                      const float* __restrict__ acsb,
                                                      short* __restrict__ G0,
                                                      short* __restrict__ G1) {
  int blk = blockIdx.x & 1023;     // c*HEADS + h
  int b = blockIdx.x >> 10;
  short* G = b ? G1 : G0;
  int h = blk & 31, c = blk >> 5;
  __shared__ __align__(16) short sXT[64][72];   // [p][l-swz] = bf16(xs(l,p)*wt(l))
  __shared__ __align__(16) short sBT[256][72];  // [n][l-swz] = B(l,n)
  __shared__ float swt[64];
  int t = threadIdx.x;
  size_t rowb = ((size_t)(b * SEQL + c * CHUNK)) * CONV_DIMN;
  size_t ab = ((size_t)(b * SEQL + c * CHUNK)) * HEADS;
  if (t < 64) {
    float a = acsb[ab + (size_t)t * HEADS + h];
    float alast = acsb[ab + (size_t)63 * HEADS + h];
    swt[t] = expf(alast - a) * dtb[ab + (size_t)t * HEADS + h];
  }
  __syncthreads();
  #pragma unroll
  for (int i = 0; i < 4; i++) {
    int e = t + 256 * i;
    int l = e >> 4, p4 = (e & 15) * 4;
    short4v v = *(const short4v*)&convb[rowb + (size_t)l * CONV_DIMN + h * HEAD_DIM + p4];
    float wt = swt[l];
    short vv[4] = {v.x, v.y, v.z, v.w};
    #pragma unroll
    for (int j = 0; j < 4; j++) {
      int p = p4 + j;
      sXT[p][((((l >> 3) ^ ((p >> 2) & 7)) << 3) | (l & 7))] = f2bf(b2f(vv[j]) * wt);
    }
  }
  #pragma unroll
  for (int i = 0; i < 16; i++) {
    int e = t + 256 * i;
    int l = e >> 6, n4 = (e & 63) * 4;
    short4v v = *(const short4v*)&convb[rowb + (size_t)l * CONV_DIMN + D_MODEL + n4];
    short vv[4] = {v.x, v.y, v.z, v.w};
    #pragma unroll
    for (int j = 0; j < 4; j++) {
      int n = n4 + j;
      sBT[n][((((l >> 3) ^ ((n >> 2) & 7)) << 3) | (l & 7))] = vv[j];
    }
  }
  __syncthreads();
  int lane = t & 63, w = t >> 6;
  int mr = lane & 15, q = lane >> 4;
  f32x4 acc[4][4] = {};
  #pragma unroll
  for (int ks = 0; ks < 2; ks++) {
    short8 af[4], bfr[4];
    #pragma unroll
    for (int mi = 0; mi < 4; mi++) {
      int p = mi * 16 + mr;
      af[mi] = *(const short8*)&sXT[p][(((ks * 4 + q) ^ ((p >> 2) & 7)) << 3)];
    }
    #pragma unroll
    for (int ni = 0; ni < 4; ni++) {
      int n = w * 64 + ni * 16 + mr;
      bfr[ni] = *(const short8*)&sBT[n][(((ks * 4 + q) ^ ((n >> 2) & 7)) << 3)];
    }
    #pragma unroll
    for (int mi = 0; mi < 4; mi++)
      #pragma unroll
      for (int ni = 0; ni < 4; ni++)
        acc[mi][ni] = __builtin_amdgcn_mfma_f32_16x16x32_bf16(af[mi], bfr[ni], acc[mi][ni], 0, 0, 0);
  }
  size_t gb = (size_t)blk * (64 * 256);
  #pragma unroll
  for (int mi = 0; mi < 4; mi++)
    #pragma unroll
    for (int ni = 0; ni < 4; ni++)
      #pragma unroll
      for (int r = 0; r < 4; r++)
        G[gb + (size_t)(mi * 16 + q * 4 + r) * 256 + w * 64 + ni * 16 + mr] = f2bf(acc[mi][ni][r]);
}

// ------- sequential chunk recursion, both batches, int4-vectorized ---------
__global__ __launch_bounds__(256) void scan_states_k(short* __restrict__ G0,
                                                     short* __restrict__ G1,
                                                     const float* __restrict__ acsb) {
  int gid = blockIdx.x * 256 + threadIdx.x;   // 512 blocks = 131072 threads
  int b = gid >> 16;
  int tid = gid & 65535;                       // 65536 threads per batch
  short* G = b ? G1 : G0;
  int n8 = tid & 31, p = (tid >> 5) & 63, h = tid >> 11;
  float S[8] = {};
  for (int c = 0; c < NC; c++) {
    size_t base = (((size_t)(c * HEADS + h) * 64) + p) * 256 + n8 * 8;
    short gs[8];
    *(int4*)gs = *(const int4*)&G[base];
    short ws8[8];
    #pragma unroll
    for (int j = 0; j < 8; j++) ws8[j] = f2bf(S[j]);
    *(int4*)&G[base] = *(int4*)ws8;
    float dec = expf(acsb[((size_t)(b * SEQL + c * CHUNK + 63)) * HEADS + h]);
    #pragma unroll
    for (int j = 0; j < 8; j++) S[j] = S[j] * dec + b2f(gs[j]);
  }
}

// ------- fused Y = Ydiag + ea_l*Yoff + D*xs, BOTH batches (grid 2048) ------
__global__ __launch_bounds__(256) void y_fused_k(const short* __restrict__ convb,
                                                 const short* __restrict__ CBb,
                                                 const short* __restrict__ G0,
                                                 const short* __restrict__ G1,
                                                 const float* __restrict__ dtb,
                                                 const float* __restrict__ acsb,
                                                 const float* __restrict__ D_skip,
                                                 float* __restrict__ Y) {
  int blk = blockIdx.x & 1023;     // c*HEADS + h
  int b = blockIdx.x >> 10;
  const short* G = b ? G1 : G0;
  int h = blk & 31, c = blk >> 5;
  __shared__ __align__(16) short sM[64][72];    // M(l,s) bf16, plain cols
  __shared__ __align__(16) short sXT[64][72];   // [p][l-swz] = xs(l,p)
  __shared__ float sacs[64], sdt[64], sea[64];
  int t = threadIdx.x;
  int lane = t & 63, w = t >> 6;
  size_t rowb = ((size_t)(b * SEQL + c * CHUNK)) * CONV_DIMN;
  size_t ab = ((size_t)(b * SEQL + c * CHUNK)) * HEADS;
  size_t cbbase = ((size_t)(b * NC + c)) * 64 * 64;
  if (t < 64) {
    float a = acsb[ab + (size_t)t * HEADS + h];
    sacs[t] = a;
    sea[t] = expf(a);
    sdt[t] = dtb[ab + (size_t)t * HEADS + h];
  }
  __syncthreads();
  // stage M(l,s) = CB * exp(acs_l - acs_s) * dt_s * [s<=l]
  #pragma unroll
  for (int i = 0; i < 16; i++) {
    int e = t + 256 * i;
    int r = e >> 6, col = e & 63;
    float m = 0.f;
    if (col <= r)
      m = b2f(CBb[cbbase + (size_t)r * 64 + col]) * expf(sacs[r] - sacs[col]) * sdt[col];
    sM[r][col] = f2bf(m);
  }
  // stage xs^T (raw)
  #pragma unroll
  for (int i = 0; i < 4; i++) {
    int e = t + 256 * i;
    int l = e >> 4, p4 = (e & 15) * 4;
    short4v v = *(const short4v*)&convb[rowb + (size_t)l * CONV_DIMN + h * HEAD_DIM + p4];
    short vv[4] = {v.x, v.y, v.z, v.w};
    #pragma unroll
    for (int j = 0; j < 4; j++) {
      int p = p4 + j;
      sXT[p][((((l >> 3) ^ ((p >> 2) & 7)) << 3) | (l & 7))] = vv[j];
    }
  }
  __syncthreads();
  int mr = lane & 15, q = lane >> 4;
  int wm = (w & 1) * 32, wn = (w >> 1) * 32;
  f32x4 acc1[2][2] = {}, acc2[2][2] = {};
  // MFMA1: Ydiag
  #pragma unroll
  for (int ks = 0; ks < 2; ks++) {
    short8 af[2], bfr[2];
    #pragma unroll
    for (int mi = 0; mi < 2; mi++)
      af[mi] = *(const short8*)&sM[wm + mi * 16 + mr][ks * 32 + q * 8];
    #pragma unroll
    for (int ni = 0; ni < 2; ni++) {
      int p = wn + ni * 16 + mr;
      bfr[ni] = *(const short8*)&sXT[p][(((ks * 4 + q) ^ ((p >> 2) & 7)) << 3)];
    }
    #pragma unroll
    for (int mi = 0; mi < 2; mi++)
      #pragma unroll
      for (int ni = 0; ni < 2; ni++)
        acc1[mi][ni] = __builtin_amdgcn_mfma_f32_16x16x32_bf16(af[mi], bfr[ni], acc1[mi][ni], 0, 0, 0);
  }
  // MFMA2: Yoff/ea -- operands direct from global (raw C rows, S rows)
  const short* Crow = convb + rowb + (D_MODEL + STATE);
  size_t gbase = (size_t)blk * (64 * 256);
  #pragma unroll
  for (int st = 0; st < 8; st++) {
    short8 af[2], bfr[2];
    #pragma unroll
    for (int mi = 0; mi < 2; mi++) {
      int l = wm + mi * 16 + mr;
      af[mi] = *(const short8*)&Crow[(size_t)l * CONV_DIMN + st * 32 + q * 8];
    }
    #pragma unroll
    for (int ni = 0; ni < 2; ni++) {
      int p = wn + ni * 16 + mr;
      bfr[ni] = *(const short8*)&G[gbase + (size_t)p * 256 + st * 32 + q * 8];
    }
    #pragma unroll
    for (int mi = 0; mi < 2; mi++)
      #pragma unroll
      for (int ni = 0; ni < 2; ni++)
        acc2[mi][ni] = __builtin_amdgcn_mfma_f32_16x16x32_bf16(af[mi], bfr[ni], acc2[mi][ni], 0, 0, 0);
  }
  // epilogue
  float dsk = D_skip[h];
  size_t ybase = ((size_t)(b * SEQL + c * CHUNK)) * D_MODEL + h * HEAD_DIM;
  #pragma unroll
  for (int mi = 0; mi < 2; mi++)
    #pragma unroll
    for (int ni = 0; ni < 2; ni++) {
      int p = wn + ni * 16 + mr;
      #pragma unroll
      for (int r = 0; r < 4; r++) {
        int l = wm + mi * 16 + q * 4 + r;
        float xsv = b2f(sXT[p][((((l >> 3) ^ ((p >> 2) & 7)) << 3) | (l & 7))]);
        Y[ybase + (size_t)l * D_MODEL + p] =
            acc1[mi][ni][r] + sea[l] * acc2[mi][ni][r] + dsk * xsv;
      }
    }
}

// ---------------- gated RMSNorm -> bf16 (z from projb) ---------------------
__global__ __launch_bounds__(256) void gated_norm_bf16_k(const float* __restrict__ Y,
                                                         const short* __restrict__ projb,
                                                         const float* __restrict__ gw,
                                                         short* __restrict__ out) {
  int row = blockIdx.x;
  int t = threadIdx.x;
  const float4* y4 = (const float4*)(Y + (size_t)row * D_MODEL);
  float4 ya = y4[2 * t], yb = y4[2 * t + 1];
  short zt[8];
  *(int4*)zt = *(const int4*)(projb + (size_t)row * PROJB_W + t * 8);
  float g[8];
  float yv[8] = {ya.x, ya.y, ya.z, ya.w, yb.x, yb.y, yb.z, yb.w};
  float ss = 0.f;
  #pragma unroll
  for (int i = 0; i < 8; i++) {
    float z = b2f(zt[i]);
    g[i] = yv[i] * (z / (1.f + expf(-z)));
    ss += g[i] * g[i];
  }
  #pragma unroll
  for (int off = 32; off > 0; off >>= 1) ss += __shfl_down(ss, off);
  __shared__ float ws_[4];
  if ((t & 63) == 0) ws_[t >> 6] = ss;
  __syncthreads();
  float tot = ws_[0] + ws_[1] + ws_[2] + ws_[3];
  float scale = rsqrtf(tot / (float)D_MODEL + EPSF);
  const float4* g4 = (const float4*)gw;
  float4 wa = g4[2 * t], wb = g4[2 * t + 1];
  float wv[8] = {wa.x, wa.y, wa.z, wa.w, wb.x, wb.y, wb.z, wb.w};
  short tmp[8];
  #pragma unroll
  for (int i = 0; i < 8; i++) tmp[i] = f2bf(g[i] * scale * wv[i]);
  *(int4*)(out + (size_t)row * D_MODEL + t * 8) = *(int4*)tmp;
}

extern "C" void kernel_launch(void* const* d_in, const int* in_sizes, int n_in,
                              void* d_out, int out_size, void* d_ws, size_t ws_size,
                              hipStream_t stream) {
  const float* x       = (const float*)d_in[0];
  const float* norm_w  = (const float*)d_in[1];
  const float* w_in    = (const float*)d_in[2];
  const float* conv_w  = (const float*)d_in[3];
  const float* conv_b  = (const float*)d_in[4];
  const float* dt_bias = (const float*)d_in[5];
  const float* A_log   = (const float*)d_in[6];
  const float* D_skip  = (const float*)d_in[7];
  const float* gnorm_w = (const float*)d_in[8];
  const float* w_out   = (const float*)d_in[9];
  const float* wo_w    = (const float*)d_in[10];
  float* out = (float*)d_out;

  // workspace (float units), total 36,700,160 fu = 140 MiB
  float* ws    = (float*)d_ws;
  short* xnb   = (short*)ws;                 // [0 .. 4,194,304 fu)  bf16 4096x2048
  short* w_inT = (short*)(ws + 4194304);     // 4,718,592 fu         bf16 4608x2048
  short* projb = (short*)(ws + 8912896);     // 9,437,184 fu         bf16 4096x4608
  short* convb = (short*)(ws + 18350080);    // 5,242,880 fu         bf16 4096x2560
  float* dtraw = ws + 23592960;              // 131,072
  float* dtb   = ws + 23724032;              // 131,072
  float* acsb  = ws + 23855104;              // 131,072
  short* CBb   = (short*)(ws + 23986176);    // 131,072 fu           bf16 64x64x64
  float* Yb    = ws + 24117248;              // 8,388,608
  short* w_outT= (short*)(ws + 32505856);    // 2,097,152 fu
  short* wo_wT = (short*)(ws + 34603008);    // 2,097,152 fu
  short* G0    = (short*)ws;                 // batch-0 states: 33.5 MB over xnb+w_inT (dead after big GEMM)
  short* G1    = (short*)out;                // batch-1 states: d_out (33.5 MB) is dead until final GEMM
  short* Yg    = convb;                      // overlays convb after y_fused
  short* t1b   = (short*)ws;                 // overlays G0 region after y_fused

  dt_gemm_k<<<BL, 256, 0, stream>>>(x, norm_w, w_in, xnb, dtraw);
  transpose_bf16_k<<<dim3(PROJB_W / 32, D_MODEL / 32), 256, 0, stream>>>(w_in, w_inT, D_MODEL, PROJB_W, PROJ_DIM);
  transpose_bf16_k<<<dim3(D_MODEL / 32, D_MODEL / 32), 256, 0, stream>>>(w_out, w_outT, D_MODEL, D_MODEL, D_MODEL);
  transpose_bf16_k<<<dim3(D_MODEL / 32, D_MODEL / 32), 256, 0, stream>>>(wo_w, wo_wT, D_MODEL, D_MODEL, D_MODEL);
  gemm8p_k<true><<<(BL / 256) * (PROJB_W / 128), 512, 0, stream>>>(xnb, w_inT, projb, BL, PROJB_W, D_MODEL);
  conv_silu_k<<<(BL * (CONV_DIMN / 8)) / 256, 256, 0, stream>>>(projb, conv_w, conv_b, convb);
  dt_acs_k<<<BATCHN * NC, 256, 0, stream>>>(dtraw, dt_bias, A_log, dtb, acsb);
  cb_k<<<BATCHN * NC, 256, 0, stream>>>(convb, CBb);
  chunk_states_k<<<BATCHN * NC * HEADS, 256, 0, stream>>>(convb, dtb, acsb, G0, G1);
  scan_states_k<<<512, 256, 0, stream>>>(G0, G1, acsb);
  y_fused_k<<<BATCHN * NC * HEADS, 256, 0, stream>>>(convb, CBb, G0, G1, dtb, acsb, D_skip, Yb);
  gated_norm_bf16_k<<<BL, 256, 0, stream>>>(Yb, projb, gnorm_w, Yg);
  gemm8p_k<true><<<(BL / 256) * (D_MODEL / 128), 512, 0, stream>>>(Yg, w_outT, t1b, BL, D_MODEL, D_MODEL);
  gemm8p_k<false><<<(BL / 256) * (D_MODEL / 128), 512, 0, stream>>>(t1b, wo_wT, out, BL, D_MODEL, D_MODEL);
}

// Round 6
// 570.859 us; speedup vs baseline: 1.0623x; 1.0607x over previous
//
#include <hip/hip_runtime.h>
#include <math.h>

#define D_MODEL 2048
#define HEADS 32
#define HEAD_DIM 64
#define STATE 256
#define KCONV 4
#define CHUNK 64
#define NC 32            // SEQ / CHUNK
#define SEQL 2048
#define BATCHN 2
#define CONV_DIMN 2560   // D_MODEL + 2*STATE
#define PROJ_DIM 4640    // D_MODEL + CONV_DIM + HEADS
#define PROJB_W 4608     // 36*128: z + xBC cols (dt handled by dtg_k)
#define EPSF 1e-5f
#define BL (BATCHN * SEQL)  // 4096 token rows

typedef __attribute__((ext_vector_type(8))) short short8;
typedef __attribute__((ext_vector_type(4))) short short4v;
typedef __attribute__((ext_vector_type(4))) float f32x4;

__device__ __forceinline__ short f2bf(float f) {
  unsigned u = __builtin_bit_cast(unsigned, f);
  u = (u + 0x7fffu + ((u >> 16) & 1u)) >> 16;   // RNE
  return (short)u;
}
__device__ __forceinline__ float b2f(short s) {
  unsigned u = ((unsigned)(unsigned short)s) << 16;
  return __builtin_bit_cast(float, u);
}
__device__ __forceinline__ void gld16(const void* g, void* l) {
  __builtin_amdgcn_global_load_lds((const __attribute__((address_space(1))) unsigned int*)g,
                                   (__attribute__((address_space(3))) unsigned int*)l,
                                   16, 0, 0);
}

// ---------------- RMSNorm -> bf16 ------------------------------------------
__global__ __launch_bounds__(256) void rmsnorm_bf16_k(const float* __restrict__ x,
                                                      const float* __restrict__ w,
                                                      short* __restrict__ out) {
  int row = blockIdx.x;
  int t = threadIdx.x;
  const float4* x4 = (const float4*)(x + (size_t)row * D_MODEL);
  float4 va = x4[2 * t], vb = x4[2 * t + 1];
  float ss = va.x * va.x + va.y * va.y + va.z * va.z + va.w * va.w +
             vb.x * vb.x + vb.y * vb.y + vb.z * vb.z + vb.w * vb.w;
  #pragma unroll
  for (int off = 32; off > 0; off >>= 1) ss += __shfl_down(ss, off);
  __shared__ float ws_[4];
  if ((t & 63) == 0) ws_[t >> 6] = ss;
  __syncthreads();
  float tot = ws_[0] + ws_[1] + ws_[2] + ws_[3];
  float scale = rsqrtf(tot / (float)D_MODEL + EPSF);
  const float4* w4 = (const float4*)w;
  float4 wa = w4[2 * t], wb = w4[2 * t + 1];
  short tmp[8];
  tmp[0] = f2bf(va.x * scale * wa.x); tmp[1] = f2bf(va.y * scale * wa.y);
  tmp[2] = f2bf(va.z * scale * wa.z); tmp[3] = f2bf(va.w * scale * wa.w);
  tmp[4] = f2bf(vb.x * scale * wb.x); tmp[5] = f2bf(vb.y * scale * wb.y);
  tmp[6] = f2bf(vb.z * scale * wb.z); tmp[7] = f2bf(vb.w * scale * wb.w);
  *(int4*)(out + (size_t)row * D_MODEL + t * 8) = *(int4*)tmp;
}

// ---------------- transpose + fp32->bf16 -----------------------------------
__global__ __launch_bounds__(256) void transpose_bf16_k(const float* __restrict__ W,
                                                        short* __restrict__ WT,
                                                        int K, int ncols, int stride) {
  __shared__ float tile[32][33];
  int bn = blockIdx.x * 32, bk = blockIdx.y * 32;
  int tx = threadIdx.x & 31, ty = threadIdx.x >> 5;  // ty 0..7
  #pragma unroll
  for (int i = 0; i < 32; i += 8) {
    int k = bk + ty + i, n = bn + tx;
    tile[ty + i][tx] = (n < ncols) ? W[(size_t)k * stride + n] : 0.f;
  }
  __syncthreads();
  #pragma unroll
  for (int i = 0; i < 32; i += 8) {
    int n = bn + ty + i, k = bk + tx;
    if (n < ncols) WT[(size_t)n * K + k] = f2bf(tile[tx][ty + i]);
  }
}

// ------- skinny MFMA dt projection: dtraw = xnb @ WdtT^T (fp32 out) --------
// 128 blocks x 32 rows; K=2048 split 512/wave across 4 waves; operands
// direct from global (L2: WdtT is 128 KB, fully resident; xnb read once).
// Cross-wave reduce via LDS.  Replaces the fused fp32 dt path whose per-row
// blocks re-read the same w_in slice 4096x (~1 GB L2 = ~30 us).
__global__ __launch_bounds__(256) void dtg_k(const short* __restrict__ xnb,
                                             const short* __restrict__ wdtT,
                                             float* __restrict__ dtraw) {
  __shared__ float red[4][32][32];
  int t = threadIdx.x;
  int lane = t & 63, w = t >> 6;
  int mr = lane & 15, q = lane >> 4;
  int m0 = blockIdx.x * 32;
  f32x4 acc[2][2] = {};
  for (int ks = 0; ks < 16; ks++) {
    int k = w * 512 + ks * 32 + q * 8;
    short8 af[2], bfr[2];
    #pragma unroll
    for (int i = 0; i < 2; i++)
      af[i] = *(const short8*)&xnb[(size_t)(m0 + i * 16 + mr) * D_MODEL + k];
    #pragma unroll
    for (int i = 0; i < 2; i++)
      bfr[i] = *(const short8*)&wdtT[(size_t)(i * 16 + mr) * D_MODEL + k];
    #pragma unroll
    for (int mi = 0; mi < 2; mi++)
      #pragma unroll
      for (int ni = 0; ni < 2; ni++)
        acc[mi][ni] = __builtin_amdgcn_mfma_f32_16x16x32_bf16(af[mi], bfr[ni], acc[mi][ni], 0, 0, 0);
  }
  // C layout: row = mi*16 + q*4 + r, col = ni*16 + mr
  #pragma unroll
  for (int mi = 0; mi < 2; mi++)
    #pragma unroll
    for (int ni = 0; ni < 2; ni++)
      #pragma unroll
      for (int r = 0; r < 4; r++)
        red[w][mi * 16 + q * 4 + r][ni * 16 + mr] = acc[mi][ni][r];
  __syncthreads();
  #pragma unroll
  for (int i = 0; i < 4; i++) {
    int e = t + 256 * i;
    int row = e >> 5, col = e & 31;
    dtraw[(size_t)(m0 + row) * HEADS + col] =
        red[0][row][col] + red[1][row][col] + red[2][row][col] + red[3][row][col];
  }
}

// ---------------- pipelined MFMA GEMM: C[M,N] = A[M,K] @ BT[N,K]^T ---------
// Round-3 proven version: tile 128x256, BK=32, 8 waves, 3-buffer rotation,
// prefetch dist 2, counted vmcnt (LPT=3), raw s_barrier, setprio, XCD
// swizzle.  72 KiB LDS -> 2 blocks/CU.  745 TF / big GEMM 103 us; the
// 2-phase plateau (27-32% MfmaUtil) was confirmed structural in rounds 4-5
// (wider per-wave tile and lockstep phase-split both failed to beat it).
template<bool BF16OUT>
__global__ __launch_bounds__(512, 4) void gemm128_k(const short* __restrict__ A,
                                                    const short* __restrict__ BT,
                                                    void* __restrict__ Cout,
                                                    int M, int N, int K) {
  constexpr int ABUF = 128 * 32;        // shorts per A buffer
  constexpr int BUFS = ABUF + 8192;     // + B 256x32 shorts = 12288 shorts
  constexpr int LPT = 3;                // gld16 per tile per thread (A1 + B2)
  __shared__ short lds[3 * BUFS];       // 72 KiB

  const int t = threadIdx.x;
  const int lane = t & 63, w = t >> 6;
  const int mr = lane & 15, q = lane >> 4;
  const int cq8 = (q ^ ((mr >> 1) & 3)) * 8;            // read k-chunk (swizzled)
  const int stj = ((lane & 3) ^ ((lane >> 3) & 3)) * 8; // stage global k-chunk
  const int str = lane >> 2;                            // stage row within 16

  // bijective XCD swizzle (all grids here are %8==0)
  const int nbx = N >> 8;
  const int nwg = nbx * (M >> 7);
  const int cpx = nwg >> 3;
  const int bid = blockIdx.x;
  const int swz = (bid & 7) * cpx + (bid >> 3);
  const int bx = swz % nbx, by = swz / nbx;
  const int m0 = by * 128, n0 = bx * 256;

  const int NT = K >> 5;   // assumes NT >= 3 (all call sites K=2048)
  f32x4 acc[8][2] = {};

  auto STAGE = [&](int tile, int buf) {
    short* dst = &lds[buf * BUFS];
    const int kb = tile * 32 + stj;
    gld16(A + (size_t)(m0 + w * 16 + str) * K + kb, dst + w * 512);
    const short* gB = BT + (size_t)(n0 + w * 32 + str) * K + kb;
    short* dB = dst + ABUF + w * 1024;
    gld16(gB, dB);
    gld16(gB + (size_t)16 * K, dB + 512);
  };

  STAGE(0, 0); STAGE(1, 1);
  asm volatile("s_waitcnt vmcnt(%0)" :: "n"(LPT) : "memory");
  __builtin_amdgcn_s_barrier();

  int bufc = 0;
  for (int tt = 0; tt < NT; ++tt) {
    const short* sA = &lds[bufc * BUFS];
    const short* sB = sA + ABUF;
    if (tt + 2 < NT) STAGE(tt + 2, bufc >= 1 ? bufc - 1 : 2);
    short8 af[4], bfr[2];
    #pragma unroll
    for (int ni = 0; ni < 2; ni++)
      bfr[ni] = *(const short8*)&sB[(w * 32 + ni * 16 + mr) * 32 + cq8];
    #pragma unroll
    for (int mi = 0; mi < 4; mi++)
      af[mi] = *(const short8*)&sA[(mi * 16 + mr) * 32 + cq8];
    __builtin_amdgcn_s_setprio(1);
    #pragma unroll
    for (int mi = 0; mi < 4; mi++)
      #pragma unroll
      for (int ni = 0; ni < 2; ni++)
        acc[mi][ni] = __builtin_amdgcn_mfma_f32_16x16x32_bf16(af[mi], bfr[ni], acc[mi][ni], 0, 0, 0);
    __builtin_amdgcn_s_setprio(0);
    #pragma unroll
    for (int mi = 0; mi < 4; mi++)
      af[mi] = *(const short8*)&sA[(64 + mi * 16 + mr) * 32 + cq8];
    __builtin_amdgcn_s_setprio(1);
    #pragma unroll
    for (int mi = 0; mi < 4; mi++)
      #pragma unroll
      for (int ni = 0; ni < 2; ni++)
        acc[4 + mi][ni] = __builtin_amdgcn_mfma_f32_16x16x32_bf16(af[mi], bfr[ni], acc[4 + mi][ni], 0, 0, 0);
    __builtin_amdgcn_s_setprio(0);
    __builtin_amdgcn_sched_barrier(0);
    if (tt + 2 < NT) asm volatile("s_waitcnt vmcnt(%0)" :: "n"(LPT) : "memory");
    else             asm volatile("s_waitcnt vmcnt(0)" ::: "memory");
    __builtin_amdgcn_s_barrier();
    bufc = (bufc == 2) ? 0 : bufc + 1;
  }

  #pragma unroll
  for (int mi = 0; mi < 8; mi++)
    #pragma unroll
    for (int ni = 0; ni < 2; ni++) {
      const int gm = m0 + mi * 16 + q * 4;
      const int gn = n0 + w * 32 + ni * 16 + mr;
      #pragma unroll
      for (int r = 0; r < 4; r++) {
        if (BF16OUT) ((short*)Cout)[(size_t)(gm + r) * N + gn] = f2bf(acc[mi][ni][r]);
        else         ((float*)Cout)[(size_t)(gm + r) * N + gn] = acc[mi][ni][r];
      }
    }
}

// ------- depthwise causal conv + bias + SiLU, 8-channel vectorized ---------
__global__ __launch_bounds__(256) void conv_silu_k(const short* __restrict__ projb,
                                                   const float* __restrict__ cw,
                                                   const float* __restrict__ cb,
                                                   short* __restrict__ out) {
  int idx = blockIdx.x * 256 + threadIdx.x;   // BL * (CONV_DIM/8) total
  int ci = idx % (CONV_DIMN / 8);
  int bt = idx / (CONV_DIMN / 8);
  int t = bt & (SEQL - 1);
  int b = bt >> 11;
  int c = ci * 8;
  float4 w4[8];
  #pragma unroll
  for (int j = 0; j < 8; j++) w4[j] = ((const float4*)cw)[c + j];
  float acc[8];
  {
    float4 b0 = ((const float4*)(cb + c))[0], b1 = ((const float4*)(cb + c))[1];
    acc[0] = b0.x; acc[1] = b0.y; acc[2] = b0.z; acc[3] = b0.w;
    acc[4] = b1.x; acc[5] = b1.y; acc[6] = b1.z; acc[7] = b1.w;
  }
  #pragma unroll
  for (int k = 0; k < KCONV; k++) {
    int tt = t - (KCONV - 1) + k;
    if (tt < 0) continue;
    short8 v = *(const short8*)&projb[((size_t)(b * SEQL + tt)) * PROJB_W + D_MODEL + c];
    #pragma unroll
    for (int j = 0; j < 8; j++) {
      float wv = (k == 0) ? w4[j].x : (k == 1) ? w4[j].y : (k == 2) ? w4[j].z : w4[j].w;
      acc[j] += b2f(v[j]) * wv;
    }
  }
  short o[8];
  #pragma unroll
  for (int j = 0; j < 8; j++) o[j] = f2bf(acc[j] / (1.f + expf(-acc[j])));
  *(int4*)&out[(size_t)bt * CONV_DIMN + c] = *(int4*)o;
}

// ---------------- dt softplus + per-chunk cumsum of A*dt (4 waves) ---------
__global__ __launch_bounds__(256) void dt_acs_k(const float* __restrict__ dtraw,
                                                const float* __restrict__ dt_bias,
                                                const float* __restrict__ A_log,
                                                float* __restrict__ dtb, float* __restrict__ acsb) {
  int bc = blockIdx.x;
  int b = bc / NC, c = bc % NC;
  int t = threadIdx.x;
  int l = t & 63, w = t >> 6;     // wave w handles heads w*8..w*8+7
  size_t base = ((size_t)(b * SEQL + c * CHUNK + l)) * HEADS;
  #pragma unroll
  for (int i = 0; i < 8; i++) {
    int h = w * 8 + i;
    float raw = dtraw[base + h] + dt_bias[h];
    float dt = raw > 20.f ? raw : log1pf(expf(raw));
    float adt = -expf(A_log[h]) * dt;
    float cs = adt;
    #pragma unroll
    for (int off = 1; off < 64; off <<= 1) {
      float v = __shfl_up(cs, off);
      if (l >= off) cs += v;
    }
    dtb[base + h] = dt;
    acsb[base + h] = cs;
  }
}

// ---------------- CB[b,c,l,s] = sum_n C(l,n)*B(s,n) -> bf16 ----------------
__global__ __launch_bounds__(256) void cb_k(const short* __restrict__ convb,
                                            short* __restrict__ CB) {
  int bc = blockIdx.x;
  int b = bc / NC, c = bc % NC;
  __shared__ float sC[64][65];
  __shared__ float sB[64][65];
  int t = threadIdx.x;
  int s = t & 63;
  int lb = (t >> 6) * 16;
  float acc[16] = {};
  size_t rowb = ((size_t)(b * SEQL + c * CHUNK)) * CONV_DIMN;
  for (int nt = 0; nt < 4; nt++) {
    __syncthreads();
    #pragma unroll
    for (int i = 0; i < 16; i++) {
      int e = t + 256 * i;
      int r = e >> 6, col = e & 63;
      sC[r][col] = b2f(convb[rowb + (size_t)r * CONV_DIMN + (D_MODEL + STATE) + nt * 64 + col]);
      sB[r][col] = b2f(convb[rowb + (size_t)r * CONV_DIMN + D_MODEL + nt * 64 + col]);
    }
    __syncthreads();
    for (int n = 0; n < 64; n++) {
      float bv = sB[s][n];
      #pragma unroll
      for (int j = 0; j < 16; j++) acc[j] += sC[lb + j][n] * bv;
    }
  }
  size_t ob = ((size_t)bc) * 64 * 64;
  #pragma unroll
  for (int j = 0; j < 16; j++) CB[ob + (size_t)(lb + j) * 64 + s] = f2bf(acc[j]);
}

// ------- chunk states via MFMA, BOTH batches in one launch (grid 2048) -----
__global__ __launch_bounds__(256) void chunk_states_k(const short* __restrict__ convb,
                                                      const float* __restrict__ dtb,
                                                      const float* __restrict__ acsb,
                                                      short* __restrict__ G0,
                                                      short* __restrict__ G1) {
  int blk = blockIdx.x & 1023;     // c*HEADS + h
  int b = blockIdx.x >> 10;
  short* G = b ? G1 : G0;
  int h = blk & 31, c = blk >> 5;
  __shared__ __align__(16) short sXT[64][72];   // [p][l-swz] = bf16(xs(l,p)*wt(l))
  __shared__ __align__(16) short sBT[256][72];  // [n][l-swz] = B(l,n)
  __shared__ float swt[64];
  int t = threadIdx.x;
  size_t rowb = ((size_t)(b * SEQL + c * CHUNK)) * CONV_DIMN;
  size_t ab = ((size_t)(b * SEQL + c * CHUNK)) * HEADS;
  if (t < 64) {
    float a = acsb[ab + (size_t)t * HEADS + h];
    float alast = acsb[ab + (size_t)63 * HEADS + h];
    swt[t] = expf(alast - a) * dtb[ab + (size_t)t * HEADS + h];
  }
  __syncthreads();
  #pragma unroll
  for (int i = 0; i < 4; i++) {
    int e = t + 256 * i;
    int l = e >> 4, p4 = (e & 15) * 4;
    short4v v = *(const short4v*)&convb[rowb + (size_t)l * CONV_DIMN + h * HEAD_DIM + p4];
    float wt = swt[l];
    short vv[4] = {v.x, v.y, v.z, v.w};
    #pragma unroll
    for (int j = 0; j < 4; j++) {
      int p = p4 + j;
      sXT[p][((((l >> 3) ^ ((p >> 2) & 7)) << 3) | (l & 7))] = f2bf(b2f(vv[j]) * wt);
    }
  }
  #pragma unroll
  for (int i = 0; i < 16; i++) {
    int e = t + 256 * i;
    int l = e >> 6, n4 = (e & 63) * 4;
    short4v v = *(const short4v*)&convb[rowb + (size_t)l * CONV_DIMN + D_MODEL + n4];
    short vv[4] = {v.x, v.y, v.z, v.w};
    #pragma unroll
    for (int j = 0; j < 4; j++) {
      int n = n4 + j;
      sBT[n][((((l >> 3) ^ ((n >> 2) & 7)) << 3) | (l & 7))] = vv[j];
    }
  }
  __syncthreads();
  int lane = t & 63, w = t >> 6;
  int mr = lane & 15, q = lane >> 4;
  f32x4 acc[4][4] = {};
  #pragma unroll
  for (int ks = 0; ks < 2; ks++) {
    short8 af[4], bfr[4];
    #pragma unroll
    for (int mi = 0; mi < 4; mi++) {
      int p = mi * 16 + mr;
      af[mi] = *(const short8*)&sXT[p][(((ks * 4 + q) ^ ((p >> 2) & 7)) << 3)];
    }
    #pragma unroll
    for (int ni = 0; ni < 4; ni++) {
      int n = w * 64 + ni * 16 + mr;
      bfr[ni] = *(const short8*)&sBT[n][(((ks * 4 + q) ^ ((n >> 2) & 7)) << 3)];
    }
    #pragma unroll
    for (int mi = 0; mi < 4; mi++)
      #pragma unroll
      for (int ni = 0; ni < 4; ni++)
        acc[mi][ni] = __builtin_amdgcn_mfma_f32_16x16x32_bf16(af[mi], bfr[ni], acc[mi][ni], 0, 0, 0);
  }
  size_t gb = (size_t)blk * (64 * 256);
  #pragma unroll
  for (int mi = 0; mi < 4; mi++)
    #pragma unroll
    for (int ni = 0; ni < 4; ni++)
      #pragma unroll
      for (int r = 0; r < 4; r++)
        G[gb + (size_t)(mi * 16 + q * 4 + r) * 256 + w * 64 + ni * 16 + mr] = f2bf(acc[mi][ni][r]);
}

// ------- sequential chunk recursion, both batches, int4-vectorized ---------
__global__ __launch_bounds__(256) void scan_states_k(short* __restrict__ G0,
                                                     short* __restrict__ G1,
                                                     const float* __restrict__ acsb) {
  int gid = blockIdx.x * 256 + threadIdx.x;   // 512 blocks = 131072 threads
  int b = gid >> 16;
  int tid = gid & 65535;                       // 65536 threads per batch
  short* G = b ? G1 : G0;
  int n8 = tid & 31, p = (tid >> 5) & 63, h = tid >> 11;
  float S[8] = {};
  for (int c = 0; c < NC; c++) {
    size_t base = (((size_t)(c * HEADS + h) * 64) + p) * 256 + n8 * 8;
    short gs[8];
    *(int4*)gs = *(const int4*)&G[base];
    short ws8[8];
    #pragma unroll
    for (int j = 0; j < 8; j++) ws8[j] = f2bf(S[j]);
    *(int4*)&G[base] = *(int4*)ws8;
    float dec = expf(acsb[((size_t)(b * SEQL + c * CHUNK + 63)) * HEADS + h]);
    #pragma unroll
    for (int j = 0; j < 8; j++) S[j] = S[j] * dec + b2f(gs[j]);
  }
}

// ------- fused Y = Ydiag + ea_l*Yoff + D*xs, BOTH batches (grid 2048) ------
__global__ __launch_bounds__(256) void y_fused_k(const short* __restrict__ convb,
                                                 const short* __restrict__ CBb,
                                                 const short* __restrict__ G0,
                                                 const short* __restrict__ G1,
                                                 const float* __restrict__ dtb,
                                                 const float* __restrict__ acsb,
                                                 const float* __restrict__ D_skip,
                                                 float* __restrict__ Y) {
  int blk = blockIdx.x & 1023;     // c*HEADS + h
  int b = blockIdx.x >> 10;
  const short* G = b ? G1 : G0;
  int h = blk & 31, c = blk >> 5;
  __shared__ __align__(16) short sM[64][72];    // M(l,s) bf16, plain cols
  __shared__ __align__(16) short sXT[64][72];   // [p][l-swz] = xs(l,p)
  __shared__ float sacs[64], sdt[64], sea[64];
  int t = threadIdx.x;
  int lane = t & 63, w = t >> 6;
  size_t rowb = ((size_t)(b * SEQL + c * CHUNK)) * CONV_DIMN;
  size_t ab = ((size_t)(b * SEQL + c * CHUNK)) * HEADS;
  size_t cbbase = ((size_t)(b * NC + c)) * 64 * 64;
  if (t < 64) {
    float a = acsb[ab + (size_t)t * HEADS + h];
    sacs[t] = a;
    sea[t] = expf(a);
    sdt[t] = dtb[ab + (size_t)t * HEADS + h];
  }
  __syncthreads();
  // stage M(l,s) = CB * exp(acs_l - acs_s) * dt_s * [s<=l]
  #pragma unroll
  for (int i = 0; i < 16; i++) {
    int e = t + 256 * i;
    int r = e >> 6, col = e & 63;
    float m = 0.f;
    if (col <= r)
      m = b2f(CBb[cbbase + (size_t)r * 64 + col]) * expf(sacs[r] - sacs[col]) * sdt[col];
    sM[r][col] = f2bf(m);
  }
  // stage xs^T (raw)
  #pragma unroll
  for (int i = 0; i < 4; i++) {
    int e = t + 256 * i;
    int l = e >> 4, p4 = (e & 15) * 4;
    short4v v = *(const short4v*)&convb[rowb + (size_t)l * CONV_DIMN + h * HEAD_DIM + p4];
    short vv[4] = {v.x, v.y, v.z, v.w};
    #pragma unroll
    for (int j = 0; j < 4; j++) {
      int p = p4 + j;
      sXT[p][((((l >> 3) ^ ((p >> 2) & 7)) << 3) | (l & 7))] = vv[j];
    }
  }
  __syncthreads();
  int mr = lane & 15, q = lane >> 4;
  int wm = (w & 1) * 32, wn = (w >> 1) * 32;
  f32x4 acc1[2][2] = {}, acc2[2][2] = {};
  // MFMA1: Ydiag
  #pragma unroll
  for (int ks = 0; ks < 2; ks++) {
    short8 af[2], bfr[2];
    #pragma unroll
    for (int mi = 0; mi < 2; mi++)
      af[mi] = *(const short8*)&sM[wm + mi * 16 + mr][ks * 32 + q * 8];
    #pragma unroll
    for (int ni = 0; ni < 2; ni++) {
      int p = wn + ni * 16 + mr;
      bfr[ni] = *(const short8*)&sXT[p][(((ks * 4 + q) ^ ((p >> 2) & 7)) << 3)];
    }
    #pragma unroll
    for (int mi = 0; mi < 2; mi++)
      #pragma unroll
      for (int ni = 0; ni < 2; ni++)
        acc1[mi][ni] = __builtin_amdgcn_mfma_f32_16x16x32_bf16(af[mi], bfr[ni], acc1[mi][ni], 0, 0, 0);
  }
  // MFMA2: Yoff/ea -- operands direct from global (raw C rows, S rows)
  const short* Crow = convb + rowb + (D_MODEL + STATE);
  size_t gbase = (size_t)blk * (64 * 256);
  #pragma unroll
  for (int st = 0; st < 8; st++) {
    short8 af[2], bfr[2];
    #pragma unroll
    for (int mi = 0; mi < 2; mi++) {
      int l = wm + mi * 16 + mr;
      af[mi] = *(const short8*)&Crow[(size_t)l * CONV_DIMN + st * 32 + q * 8];
    }
    #pragma unroll
    for (int ni = 0; ni < 2; ni++) {
      int p = wn + ni * 16 + mr;
      bfr[ni] = *(const short8*)&G[gbase + (size_t)p * 256 + st * 32 + q * 8];
    }
    #pragma unroll
    for (int mi = 0; mi < 2; mi++)
      #pragma unroll
      for (int ni = 0; ni < 2; ni++)
        acc2[mi][ni] = __builtin_amdgcn_mfma_f32_16x16x32_bf16(af[mi], bfr[ni], acc2[mi][ni], 0, 0, 0);
  }
  // epilogue
  float dsk = D_skip[h];
  size_t ybase = ((size_t)(b * SEQL + c * CHUNK)) * D_MODEL + h * HEAD_DIM;
  #pragma unroll
  for (int mi = 0; mi < 2; mi++)
    #pragma unroll
    for (int ni = 0; ni < 2; ni++) {
      int p = wn + ni * 16 + mr;
      #pragma unroll
      for (int r = 0; r < 4; r++) {
        int l = wm + mi * 16 + q * 4 + r;
        float xsv = b2f(sXT[p][((((l >> 3) ^ ((p >> 2) & 7)) << 3) | (l & 7))]);
        Y[ybase + (size_t)l * D_MODEL + p] =
            acc1[mi][ni][r] + sea[l] * acc2[mi][ni][r] + dsk * xsv;
      }
    }
}

// ---------------- gated RMSNorm -> bf16 (z from projb) ---------------------
__global__ __launch_bounds__(256) void gated_norm_bf16_k(const float* __restrict__ Y,
                                                         const short* __restrict__ projb,
                                                         const float* __restrict__ gw,
                                                         short* __restrict__ out) {
  int row = blockIdx.x;
  int t = threadIdx.x;
  const float4* y4 = (const float4*)(Y + (size_t)row * D_MODEL);
  float4 ya = y4[2 * t], yb = y4[2 * t + 1];
  short zt[8];
  *(int4*)zt = *(const int4*)(projb + (size_t)row * PROJB_W + t * 8);
  float g[8];
  float yv[8] = {ya.x, ya.y, ya.z, ya.w, yb.x, yb.y, yb.z, yb.w};
  float ss = 0.f;
  #pragma unroll
  for (int i = 0; i < 8; i++) {
    float z = b2f(zt[i]);
    g[i] = yv[i] * (z / (1.f + expf(-z)));
    ss += g[i] * g[i];
  }
  #pragma unroll
  for (int off = 32; off > 0; off >>= 1) ss += __shfl_down(ss, off);
  __shared__ float ws_[4];
  if ((t & 63) == 0) ws_[t >> 6] = ss;
  __syncthreads();
  float tot = ws_[0] + ws_[1] + ws_[2] + ws_[3];
  float scale = rsqrtf(tot / (float)D_MODEL + EPSF);
  const float4* g4 = (const float4*)gw;
  float4 wa = g4[2 * t], wb = g4[2 * t + 1];
  float wv[8] = {wa.x, wa.y, wa.z, wa.w, wb.x, wb.y, wb.z, wb.w};
  short tmp[8];
  #pragma unroll
  for (int i = 0; i < 8; i++) tmp[i] = f2bf(g[i] * scale * wv[i]);
  *(int4*)(out + (size_t)row * D_MODEL + t * 8) = *(int4*)tmp;
}

extern "C" void kernel_launch(void* const* d_in, const int* in_sizes, int n_in,
                              void* d_out, int out_size, void* d_ws, size_t ws_size,
                              hipStream_t stream) {
  const float* x       = (const float*)d_in[0];
  const float* norm_w  = (const float*)d_in[1];
  const float* w_in    = (const float*)d_in[2];
  const float* conv_w  = (const float*)d_in[3];
  const float* conv_b  = (const float*)d_in[4];
  const float* dt_bias = (const float*)d_in[5];
  const float* A_log   = (const float*)d_in[6];
  const float* D_skip  = (const float*)d_in[7];
  const float* gnorm_w = (const float*)d_in[8];
  const float* w_out   = (const float*)d_in[9];
  const float* wo_w    = (const float*)d_in[10];
  float* out = (float*)d_out;

  // workspace (float units), total 36,700,160 fu = 140 MiB
  float* ws    = (float*)d_ws;
  short* xnb   = (short*)ws;                 // [0 .. 4,194,304 fu)  bf16 4096x2048
  short* w_inT = (short*)(ws + 4194304);     // 4,718,592 fu         bf16 4608x2048
  short* projb = (short*)(ws + 8912896);     // 9,437,184 fu         bf16 4096x4608
  short* convb = (short*)(ws + 18350080);    // 5,242,880 fu         bf16 4096x2560
  float* dtraw = ws + 23592960;              // 131,072
  float* dtb   = ws + 23724032;              // 131,072
  float* acsb  = ws + 23855104;              // 131,072
  short* CBb   = (short*)(ws + 23986176);    // 131,072 fu           bf16 64x64x64
  float* Yb    = ws + 24117248;              // 8,388,608
  short* w_outT= (short*)(ws + 32505856);    // 2,097,152 fu
  short* wo_wT = (short*)(ws + 34603008);    // 2,097,152 fu
  short* wdtT  = (short*)dtb;                // 32x2048 bf16 (32,768 fu) parked in dtb
                                             // (dtb only written later by dt_acs_k)
  short* G0    = (short*)ws;                 // batch-0 states: 33.5 MB over xnb+w_inT (dead after big GEMM)
  short* G1    = (short*)out;                // batch-1 states: d_out (33.5 MB) is dead until final GEMM
  short* Yg    = convb;                      // overlays convb after y_fused
  short* t1b   = (short*)ws;                 // overlays G0 region after y_fused

  rmsnorm_bf16_k<<<BL, 256, 0, stream>>>(x, norm_w, xnb);
  transpose_bf16_k<<<dim3(PROJB_W / 32, D_MODEL / 32), 256, 0, stream>>>(w_in, w_inT, D_MODEL, PROJB_W, PROJ_DIM);
  transpose_bf16_k<<<dim3(1, D_MODEL / 32), 256, 0, stream>>>(w_in + D_MODEL + CONV_DIMN, wdtT, D_MODEL, HEADS, PROJ_DIM);
  transpose_bf16_k<<<dim3(D_MODEL / 32, D_MODEL / 32), 256, 0, stream>>>(w_out, w_outT, D_MODEL, D_MODEL, D_MODEL);
  transpose_bf16_k<<<dim3(D_MODEL / 32, D_MODEL / 32), 256, 0, stream>>>(wo_w, wo_wT, D_MODEL, D_MODEL, D_MODEL);
  dtg_k<<<BL / 32, 256, 0, stream>>>(xnb, wdtT, dtraw);
  gemm128_k<true><<<(BL / 128) * (PROJB_W / 256), 512, 0, stream>>>(xnb, w_inT, projb, BL, PROJB_W, D_MODEL);
  conv_silu_k<<<(BL * (CONV_DIMN / 8)) / 256, 256, 0, stream>>>(projb, conv_w, conv_b, convb);
  dt_acs_k<<<BATCHN * NC, 256, 0, stream>>>(dtraw, dt_bias, A_log, dtb, acsb);
  cb_k<<<BATCHN * NC, 256, 0, stream>>>(convb, CBb);
  chunk_states_k<<<BATCHN * NC * HEADS, 256, 0, stream>>>(convb, dtb, acsb, G0, G1);
  scan_states_k<<<512, 256, 0, stream>>>(G0, G1, acsb);
  y_fused_k<<<BATCHN * NC * HEADS, 256, 0, stream>>>(convb, CBb, G0, G1, dtb, acsb, D_skip, Yb);
  gated_norm_bf16_k<<<BL, 256, 0, stream>>>(Yb, projb, gnorm_w, Yg);
  gemm128_k<true><<<(BL / 128) * (D_MODEL / 256), 512, 0, stream>>>(Yg, w_outT, t1b, BL, D_MODEL, D_MODEL);
  gemm128_k<false><<<(BL / 128) * (D_MODEL / 256), 512, 0, stream>>>(t1b, wo_wT, out, BL, D_MODEL, D_MODEL);
}

// Round 7
// 570.800 us; speedup vs baseline: 1.0624x; 1.0001x over previous
//
#include <hip/hip_runtime.h>
#include <math.h>

#define D_MODEL 2048
#define HEADS 32
#define HEAD_DIM 64
#define STATE 256
#define KCONV 4
#define CHUNK 64
#define NC 32            // SEQ / CHUNK
#define SEQL 2048
#define BATCHN 2
#define CONV_DIMN 2560   // D_MODEL + 2*STATE
#define PROJ_DIM 4640    // D_MODEL + CONV_DIM + HEADS
#define PROJB_W 4608     // 36*128: z + xBC cols (dt handled by dtg_k)
#define EPSF 1e-5f
#define BL (BATCHN * SEQL)  // 4096 token rows

typedef __attribute__((ext_vector_type(8))) short short8;
typedef __attribute__((ext_vector_type(4))) short short4v;
typedef __attribute__((ext_vector_type(4))) float f32x4;

__device__ __forceinline__ short f2bf(float f) {
  unsigned u = __builtin_bit_cast(unsigned, f);
  u = (u + 0x7fffu + ((u >> 16) & 1u)) >> 16;   // RNE
  return (short)u;
}
__device__ __forceinline__ float b2f(short s) {
  unsigned u = ((unsigned)(unsigned short)s) << 16;
  return __builtin_bit_cast(float, u);
}
__device__ __forceinline__ void gld16(const void* g, void* l) {
  __builtin_amdgcn_global_load_lds((const __attribute__((address_space(1))) unsigned int*)g,
                                   (__attribute__((address_space(3))) unsigned int*)l,
                                   16, 0, 0);
}

// ---------------- RMSNorm -> bf16 ------------------------------------------
__global__ __launch_bounds__(256) void rmsnorm_bf16_k(const float* __restrict__ x,
                                                      const float* __restrict__ w,
                                                      short* __restrict__ out) {
  int row = blockIdx.x;
  int t = threadIdx.x;
  const float4* x4 = (const float4*)(x + (size_t)row * D_MODEL);
  float4 va = x4[2 * t], vb = x4[2 * t + 1];
  float ss = va.x * va.x + va.y * va.y + va.z * va.z + va.w * va.w +
             vb.x * vb.x + vb.y * vb.y + vb.z * vb.z + vb.w * vb.w;
  #pragma unroll
  for (int off = 32; off > 0; off >>= 1) ss += __shfl_down(ss, off);
  __shared__ float ws_[4];
  if ((t & 63) == 0) ws_[t >> 6] = ss;
  __syncthreads();
  float tot = ws_[0] + ws_[1] + ws_[2] + ws_[3];
  float scale = rsqrtf(tot / (float)D_MODEL + EPSF);
  const float4* w4 = (const float4*)w;
  float4 wa = w4[2 * t], wb = w4[2 * t + 1];
  short tmp[8];
  tmp[0] = f2bf(va.x * scale * wa.x); tmp[1] = f2bf(va.y * scale * wa.y);
  tmp[2] = f2bf(va.z * scale * wa.z); tmp[3] = f2bf(va.w * scale * wa.w);
  tmp[4] = f2bf(vb.x * scale * wb.x); tmp[5] = f2bf(vb.y * scale * wb.y);
  tmp[6] = f2bf(vb.z * scale * wb.z); tmp[7] = f2bf(vb.w * scale * wb.w);
  *(int4*)(out + (size_t)row * D_MODEL + t * 8) = *(int4*)tmp;
}

// ---------------- transpose + fp32->bf16 -----------------------------------
__global__ __launch_bounds__(256) void transpose_bf16_k(const float* __restrict__ W,
                                                        short* __restrict__ WT,
                                                        int K, int ncols, int stride) {
  __shared__ float tile[32][33];
  int bn = blockIdx.x * 32, bk = blockIdx.y * 32;
  int tx = threadIdx.x & 31, ty = threadIdx.x >> 5;  // ty 0..7
  #pragma unroll
  for (int i = 0; i < 32; i += 8) {
    int k = bk + ty + i, n = bn + tx;
    tile[ty + i][tx] = (n < ncols) ? W[(size_t)k * stride + n] : 0.f;
  }
  __syncthreads();
  #pragma unroll
  for (int i = 0; i < 32; i += 8) {
    int n = bn + ty + i, k = bk + tx;
    if (n < ncols) WT[(size_t)n * K + k] = f2bf(tile[tx][ty + i]);
  }
}

// ------- skinny MFMA dt projection: dtraw = xnb @ WdtT^T (fp32 out) --------
__global__ __launch_bounds__(256) void dtg_k(const short* __restrict__ xnb,
                                             const short* __restrict__ wdtT,
                                             float* __restrict__ dtraw) {
  __shared__ float red[4][32][32];
  int t = threadIdx.x;
  int lane = t & 63, w = t >> 6;
  int mr = lane & 15, q = lane >> 4;
  int m0 = blockIdx.x * 32;
  f32x4 acc[2][2] = {};
  for (int ks = 0; ks < 16; ks++) {
    int k = w * 512 + ks * 32 + q * 8;
    short8 af[2], bfr[2];
    #pragma unroll
    for (int i = 0; i < 2; i++)
      af[i] = *(const short8*)&xnb[(size_t)(m0 + i * 16 + mr) * D_MODEL + k];
    #pragma unroll
    for (int i = 0; i < 2; i++)
      bfr[i] = *(const short8*)&wdtT[(size_t)(i * 16 + mr) * D_MODEL + k];
    #pragma unroll
    for (int mi = 0; mi < 2; mi++)
      #pragma unroll
      for (int ni = 0; ni < 2; ni++)
        acc[mi][ni] = __builtin_amdgcn_mfma_f32_16x16x32_bf16(af[mi], bfr[ni], acc[mi][ni], 0, 0, 0);
  }
  #pragma unroll
  for (int mi = 0; mi < 2; mi++)
    #pragma unroll
    for (int ni = 0; ni < 2; ni++)
      #pragma unroll
      for (int r = 0; r < 4; r++)
        red[w][mi * 16 + q * 4 + r][ni * 16 + mr] = acc[mi][ni][r];
  __syncthreads();
  #pragma unroll
  for (int i = 0; i < 4; i++) {
    int e = t + 256 * i;
    int row = e >> 5, col = e & 31;
    dtraw[(size_t)(m0 + row) * HEADS + col] =
        red[0][row][col] + red[1][row][col] + red[2][row][col] + red[3][row][col];
  }
}

// ---------------- pipelined MFMA GEMM: C[M,N] = A[M,K] @ BT[N,K]^T ---------
// Tile 128x256, BK=32, 8 waves, 3-buffer rotation, dist-2 prefetch, counted
// vmcnt (LPT=3), raw s_barrier, setprio, XCD swizzle. 72 KiB -> 2 blocks/CU.
template<bool BF16OUT>
__global__ __launch_bounds__(512, 4) void gemm128_k(const short* __restrict__ A,
                                                    const short* __restrict__ BT,
                                                    void* __restrict__ Cout,
                                                    int M, int N, int K) {
  constexpr int ABUF = 128 * 32;        // shorts per A buffer
  constexpr int BUFS = ABUF + 8192;     // + B 256x32 shorts = 12288 shorts
  constexpr int LPT = 3;                // gld16 per tile per thread (A1 + B2)
  __shared__ short lds[3 * BUFS];       // 72 KiB

  const int t = threadIdx.x;
  const int lane = t & 63, w = t >> 6;
  const int mr = lane & 15, q = lane >> 4;
  const int cq8 = (q ^ ((mr >> 1) & 3)) * 8;            // read k-chunk (swizzled)
  const int stj = ((lane & 3) ^ ((lane >> 3) & 3)) * 8; // stage global k-chunk
  const int str = lane >> 2;                            // stage row within 16

  // bijective XCD swizzle (all grids here are %8==0)
  const int nbx = N >> 8;
  const int nwg = nbx * (M >> 7);
  const int cpx = nwg >> 3;
  const int bid = blockIdx.x;
  const int swz = (bid & 7) * cpx + (bid >> 3);
  const int bx = swz % nbx, by = swz / nbx;
  const int m0 = by * 128, n0 = bx * 256;

  const int NT = K >> 5;   // assumes NT >= 3 (all call sites K=2048)
  f32x4 acc[8][2] = {};

  auto STAGE = [&](int tile, int buf) {
    short* dst = &lds[buf * BUFS];
    const int kb = tile * 32 + stj;
    gld16(A + (size_t)(m0 + w * 16 + str) * K + kb, dst + w * 512);
    const short* gB = BT + (size_t)(n0 + w * 32 + str) * K + kb;
    short* dB = dst + ABUF + w * 1024;
    gld16(gB, dB);
    gld16(gB + (size_t)16 * K, dB + 512);
  };

  STAGE(0, 0); STAGE(1, 1);
  asm volatile("s_waitcnt vmcnt(%0)" :: "n"(LPT) : "memory");
  __builtin_amdgcn_s_barrier();

  int bufc = 0;
  for (int tt = 0; tt < NT; ++tt) {
    const short* sA = &lds[bufc * BUFS];
    const short* sB = sA + ABUF;
    if (tt + 2 < NT) STAGE(tt + 2, bufc >= 1 ? bufc - 1 : 2);
    short8 af[4], bfr[2];
    #pragma unroll
    for (int ni = 0; ni < 2; ni++)
      bfr[ni] = *(const short8*)&sB[(w * 32 + ni * 16 + mr) * 32 + cq8];
    #pragma unroll
    for (int mi = 0; mi < 4; mi++)
      af[mi] = *(const short8*)&sA[(mi * 16 + mr) * 32 + cq8];
    __builtin_amdgcn_s_setprio(1);
    #pragma unroll
    for (int mi = 0; mi < 4; mi++)
      #pragma unroll
      for (int ni = 0; ni < 2; ni++)
        acc[mi][ni] = __builtin_amdgcn_mfma_f32_16x16x32_bf16(af[mi], bfr[ni], acc[mi][ni], 0, 0, 0);
    __builtin_amdgcn_s_setprio(0);
    #pragma unroll
    for (int mi = 0; mi < 4; mi++)
      af[mi] = *(const short8*)&sA[(64 + mi * 16 + mr) * 32 + cq8];
    __builtin_amdgcn_s_setprio(1);
    #pragma unroll
    for (int mi = 0; mi < 4; mi++)
      #pragma unroll
      for (int ni = 0; ni < 2; ni++)
        acc[4 + mi][ni] = __builtin_amdgcn_mfma_f32_16x16x32_bf16(af[mi], bfr[ni], acc[4 + mi][ni], 0, 0, 0);
    __builtin_amdgcn_s_setprio(0);
    __builtin_amdgcn_sched_barrier(0);
    if (tt + 2 < NT) asm volatile("s_waitcnt vmcnt(%0)" :: "n"(LPT) : "memory");
    else             asm volatile("s_waitcnt vmcnt(0)" ::: "memory");
    __builtin_amdgcn_s_barrier();
    bufc = (bufc == 2) ? 0 : bufc + 1;
  }

  #pragma unroll
  for (int mi = 0; mi < 8; mi++)
    #pragma unroll
    for (int ni = 0; ni < 2; ni++) {
      const int gm = m0 + mi * 16 + q * 4;
      const int gn = n0 + w * 32 + ni * 16 + mr;
      #pragma unroll
      for (int r = 0; r < 4; r++) {
        if (BF16OUT) ((short*)Cout)[(size_t)(gm + r) * N + gn] = f2bf(acc[mi][ni][r]);
        else         ((float*)Cout)[(size_t)(gm + r) * N + gn] = acc[mi][ni][r];
      }
    }
}

// ------- 128x128-tile variant for the N=2048 tail GEMMs --------------------
// Same schedule/swizzle/hazard structure as gemm128_k, but 4 waves (256
// threads), per-wave 128x32 (identical fragment geometry), B tile 128x32.
// LDS 3 x 16 KiB = 48 KiB -> 3 blocks/CU capacity; tail grids become
// 32x16 = 512 blocks = 2/CU EXACTLY -- restoring the co-residency that the
// 256-block (1/CU) tails lacked (a solo block cannot hide its own 2-phase
// stage+barrier stalls; a partner block can -- the round-2 mechanism).
template<bool BF16OUT>
__global__ __launch_bounds__(256, 3) void gemm_t128_k(const short* __restrict__ A,
                                                      const short* __restrict__ BT,
                                                      void* __restrict__ Cout,
                                                      int M, int N, int K) {
  constexpr int ABUF = 128 * 32;        // 4096 shorts
  constexpr int BUFS = ABUF + 128 * 32; // 8192 shorts (16 KiB)
  constexpr int LPT = 4;                // gld16 per tile per thread (A2 + B2)
  __shared__ short lds[3 * BUFS];       // 48 KiB

  const int t = threadIdx.x;
  const int lane = t & 63, w = t >> 6;  // 4 waves
  const int mr = lane & 15, q = lane >> 4;
  const int cq8 = (q ^ ((mr >> 1) & 3)) * 8;
  const int stj = ((lane & 3) ^ ((lane >> 3) & 3)) * 8;
  const int str = lane >> 2;

  // bijective XCD swizzle (grids %8==0)
  const int nbx = N >> 7;
  const int nwg = nbx * (M >> 7);
  const int cpx = nwg >> 3;
  const int bid = blockIdx.x;
  const int swz = (bid & 7) * cpx + (bid >> 3);
  const int bx = swz % nbx, by = swz / nbx;
  const int m0 = by * 128, n0 = bx * 128;

  const int NT = K >> 5;
  f32x4 acc[8][2] = {};

  auto STAGE = [&](int tile, int buf) {
    short* dst = &lds[buf * BUFS];
    const int kb = tile * 32 + stj;
    #pragma unroll
    for (int cc = 0; cc < 2; cc++) {
      gld16(A + (size_t)(m0 + w * 32 + cc * 16 + str) * K + kb,
            dst + (w * 32 + cc * 16) * 32);
      gld16(BT + (size_t)(n0 + w * 32 + cc * 16 + str) * K + kb,
            dst + ABUF + (w * 32 + cc * 16) * 32);
    }
  };

  STAGE(0, 0); STAGE(1, 1);
  asm volatile("s_waitcnt vmcnt(%0)" :: "n"(LPT) : "memory");
  __builtin_amdgcn_s_barrier();

  int bufc = 0;
  for (int tt = 0; tt < NT; ++tt) {
    const short* sA = &lds[bufc * BUFS];
    const short* sB = sA + ABUF;
    if (tt + 2 < NT) STAGE(tt + 2, bufc >= 1 ? bufc - 1 : 2);
    short8 af[4], bfr[2];
    #pragma unroll
    for (int ni = 0; ni < 2; ni++)
      bfr[ni] = *(const short8*)&sB[(w * 32 + ni * 16 + mr) * 32 + cq8];
    #pragma unroll
    for (int mi = 0; mi < 4; mi++)
      af[mi] = *(const short8*)&sA[(mi * 16 + mr) * 32 + cq8];
    __builtin_amdgcn_s_setprio(1);
    #pragma unroll
    for (int mi = 0; mi < 4; mi++)
      #pragma unroll
      for (int ni = 0; ni < 2; ni++)
        acc[mi][ni] = __builtin_amdgcn_mfma_f32_16x16x32_bf16(af[mi], bfr[ni], acc[mi][ni], 0, 0, 0);
    __builtin_amdgcn_s_setprio(0);
    #pragma unroll
    for (int mi = 0; mi < 4; mi++)
      af[mi] = *(const short8*)&sA[(64 + mi * 16 + mr) * 32 + cq8];
    __builtin_amdgcn_s_setprio(1);
    #pragma unroll
    for (int mi = 0; mi < 4; mi++)
      #pragma unroll
      for (int ni = 0; ni < 2; ni++)
        acc[4 + mi][ni] = __builtin_amdgcn_mfma_f32_16x16x32_bf16(af[mi], bfr[ni], acc[4 + mi][ni], 0, 0, 0);
    __builtin_amdgcn_s_setprio(0);
    __builtin_amdgcn_sched_barrier(0);
    if (tt + 2 < NT) asm volatile("s_waitcnt vmcnt(%0)" :: "n"(LPT) : "memory");
    else             asm volatile("s_waitcnt vmcnt(0)" ::: "memory");
    __builtin_amdgcn_s_barrier();
    bufc = (bufc == 2) ? 0 : bufc + 1;
  }

  #pragma unroll
  for (int mi = 0; mi < 8; mi++)
    #pragma unroll
    for (int ni = 0; ni < 2; ni++) {
      const int gm = m0 + mi * 16 + q * 4;
      const int gn = n0 + w * 32 + ni * 16 + mr;
      #pragma unroll
      for (int r = 0; r < 4; r++) {
        if (BF16OUT) ((short*)Cout)[(size_t)(gm + r) * N + gn] = f2bf(acc[mi][ni][r]);
        else         ((float*)Cout)[(size_t)(gm + r) * N + gn] = acc[mi][ni][r];
      }
    }
}

// ------- depthwise causal conv + bias + SiLU, 8-channel vectorized ---------
__global__ __launch_bounds__(256) void conv_silu_k(const short* __restrict__ projb,
                                                   const float* __restrict__ cw,
                                                   const float* __restrict__ cb,
                                                   short* __restrict__ out) {
  int idx = blockIdx.x * 256 + threadIdx.x;   // BL * (CONV_DIM/8) total
  int ci = idx % (CONV_DIMN / 8);
  int bt = idx / (CONV_DIMN / 8);
  int t = bt & (SEQL - 1);
  int b = bt >> 11;
  int c = ci * 8;
  float4 w4[8];
  #pragma unroll
  for (int j = 0; j < 8; j++) w4[j] = ((const float4*)cw)[c + j];
  float acc[8];
  {
    float4 b0 = ((const float4*)(cb + c))[0], b1 = ((const float4*)(cb + c))[1];
    acc[0] = b0.x; acc[1] = b0.y; acc[2] = b0.z; acc[3] = b0.w;
    acc[4] = b1.x; acc[5] = b1.y; acc[6] = b1.z; acc[7] = b1.w;
  }
  #pragma unroll
  for (int k = 0; k < KCONV; k++) {
    int tt = t - (KCONV - 1) + k;
    if (tt < 0) continue;
    short8 v = *(const short8*)&projb[((size_t)(b * SEQL + tt)) * PROJB_W + D_MODEL + c];
    #pragma unroll
    for (int j = 0; j < 8; j++) {
      float wv = (k == 0) ? w4[j].x : (k == 1) ? w4[j].y : (k == 2) ? w4[j].z : w4[j].w;
      acc[j] += b2f(v[j]) * wv;
    }
  }
  short o[8];
  #pragma unroll
  for (int j = 0; j < 8; j++) o[j] = f2bf(acc[j] / (1.f + expf(-acc[j])));
  *(int4*)&out[(size_t)bt * CONV_DIMN + c] = *(int4*)o;
}

// ---------------- dt softplus + per-chunk cumsum of A*dt (4 waves) ---------
__global__ __launch_bounds__(256) void dt_acs_k(const float* __restrict__ dtraw,
                                                const float* __restrict__ dt_bias,
                                                const float* __restrict__ A_log,
                                                float* __restrict__ dtb, float* __restrict__ acsb) {
  int bc = blockIdx.x;
  int b = bc / NC, c = bc % NC;
  int t = threadIdx.x;
  int l = t & 63, w = t >> 6;     // wave w handles heads w*8..w*8+7
  size_t base = ((size_t)(b * SEQL + c * CHUNK + l)) * HEADS;
  #pragma unroll
  for (int i = 0; i < 8; i++) {
    int h = w * 8 + i;
    float raw = dtraw[base + h] + dt_bias[h];
    float dt = raw > 20.f ? raw : log1pf(expf(raw));
    float adt = -expf(A_log[h]) * dt;
    float cs = adt;
    #pragma unroll
    for (int off = 1; off < 64; off <<= 1) {
      float v = __shfl_up(cs, off);
      if (l >= off) cs += v;
    }
    dtb[base + h] = dt;
    acsb[base + h] = cs;
  }
}

// ---------------- CB[b,c,l,s] = sum_n C(l,n)*B(s,n) -> bf16 ----------------
__global__ __launch_bounds__(256) void cb_k(const short* __restrict__ convb,
                                            short* __restrict__ CB) {
  int bc = blockIdx.x;
  int b = bc / NC, c = bc % NC;
  __shared__ float sC[64][65];
  __shared__ float sB[64][65];
  int t = threadIdx.x;
  int s = t & 63;
  int lb = (t >> 6) * 16;
  float acc[16] = {};
  size_t rowb = ((size_t)(b * SEQL + c * CHUNK)) * CONV_DIMN;
  for (int nt = 0; nt < 4; nt++) {
    __syncthreads();
    #pragma unroll
    for (int i = 0; i < 16; i++) {
      int e = t + 256 * i;
      int r = e >> 6, col = e & 63;
      sC[r][col] = b2f(convb[rowb + (size_t)r * CONV_DIMN + (D_MODEL + STATE) + nt * 64 + col]);
      sB[r][col] = b2f(convb[rowb + (size_t)r * CONV_DIMN + D_MODEL + nt * 64 + col]);
    }
    __syncthreads();
    for (int n = 0; n < 64; n++) {
      float bv = sB[s][n];
      #pragma unroll
      for (int j = 0; j < 16; j++) acc[j] += sC[lb + j][n] * bv;
    }
  }
  size_t ob = ((size_t)bc) * 64 * 64;
  #pragma unroll
  for (int j = 0; j < 16; j++) CB[ob + (size_t)(lb + j) * 64 + s] = f2bf(acc[j]);
}

// ------- chunk states via MFMA, BOTH batches in one launch (grid 2048) -----
__global__ __launch_bounds__(256) void chunk_states_k(const short* __restrict__ convb,
                                                      const float* __restrict__ dtb,
                                                      const float* __restrict__ acsb,
                                                      short* __restrict__ G0,
                                                      short* __restrict__ G1) {
  int blk = blockIdx.x & 1023;     // c*HEADS + h
  int b = blockIdx.x >> 10;
  short* G = b ? G1 : G0;
  int h = blk & 31, c = blk >> 5;
  __shared__ __align__(16) short sXT[64][72];   // [p][l-swz] = bf16(xs(l,p)*wt(l))
  __shared__ __align__(16) short sBT[256][72];  // [n][l-swz] = B(l,n)
  __shared__ float swt[64];
  int t = threadIdx.x;
  size_t rowb = ((size_t)(b * SEQL + c * CHUNK)) * CONV_DIMN;
  size_t ab = ((size_t)(b * SEQL + c * CHUNK)) * HEADS;
  if (t < 64) {
    float a = acsb[ab + (size_t)t * HEADS + h];
    float alast = acsb[ab + (size_t)63 * HEADS + h];
    swt[t] = expf(alast - a) * dtb[ab + (size_t)t * HEADS + h];
  }
  __syncthreads();
  #pragma unroll
  for (int i = 0; i < 4; i++) {
    int e = t + 256 * i;
    int l = e >> 4, p4 = (e & 15) * 4;
    short4v v = *(const short4v*)&convb[rowb + (size_t)l * CONV_DIMN + h * HEAD_DIM + p4];
    float wt = swt[l];
    short vv[4] = {v.x, v.y, v.z, v.w};
    #pragma unroll
    for (int j = 0; j < 4; j++) {
      int p = p4 + j;
      sXT[p][((((l >> 3) ^ ((p >> 2) & 7)) << 3) | (l & 7))] = f2bf(b2f(vv[j]) * wt);
    }
  }
  #pragma unroll
  for (int i = 0; i < 16; i++) {
    int e = t + 256 * i;
    int l = e >> 6, n4 = (e & 63) * 4;
    short4v v = *(const short4v*)&convb[rowb + (size_t)l * CONV_DIMN + D_MODEL + n4];
    short vv[4] = {v.x, v.y, v.z, v.w};
    #pragma unroll
    for (int j = 0; j < 4; j++) {
      int n = n4 + j;
      sBT[n][((((l >> 3) ^ ((n >> 2) & 7)) << 3) | (l & 7))] = vv[j];
    }
  }
  __syncthreads();
  int lane = t & 63, w = t >> 6;
  int mr = lane & 15, q = lane >> 4;
  f32x4 acc[4][4] = {};
  #pragma unroll
  for (int ks = 0; ks < 2; ks++) {
    short8 af[4], bfr[4];
    #pragma unroll
    for (int mi = 0; mi < 4; mi++) {
      int p = mi * 16 + mr;
      af[mi] = *(const short8*)&sXT[p][(((ks * 4 + q) ^ ((p >> 2) & 7)) << 3)];
    }
    #pragma unroll
    for (int ni = 0; ni < 4; ni++) {
      int n = w * 64 + ni * 16 + mr;
      bfr[ni] = *(const short8*)&sBT[n][(((ks * 4 + q) ^ ((n >> 2) & 7)) << 3)];
    }
    #pragma unroll
    for (int mi = 0; mi < 4; mi++)
      #pragma unroll
      for (int ni = 0; ni < 4; ni++)
        acc[mi][ni] = __builtin_amdgcn_mfma_f32_16x16x32_bf16(af[mi], bfr[ni], acc[mi][ni], 0, 0, 0);
  }
  size_t gb = (size_t)blk * (64 * 256);
  #pragma unroll
  for (int mi = 0; mi < 4; mi++)
    #pragma unroll
    for (int ni = 0; ni < 4; ni++)
      #pragma unroll
      for (int r = 0; r < 4; r++)
        G[gb + (size_t)(mi * 16 + q * 4 + r) * 256 + w * 64 + ni * 16 + mr] = f2bf(acc[mi][ni][r]);
}

// ------- sequential chunk recursion, both batches, int4-vectorized ---------
__global__ __launch_bounds__(256) void scan_states_k(short* __restrict__ G0,
                                                     short* __restrict__ G1,
                                                     const float* __restrict__ acsb) {
  int gid = blockIdx.x * 256 + threadIdx.x;   // 512 blocks = 131072 threads
  int b = gid >> 16;
  int tid = gid & 65535;                       // 65536 threads per batch
  short* G = b ? G1 : G0;
  int n8 = tid & 31, p = (tid >> 5) & 63, h = tid >> 11;
  float S[8] = {};
  for (int c = 0; c < NC; c++) {
    size_t base = (((size_t)(c * HEADS + h) * 64) + p) * 256 + n8 * 8;
    short gs[8];
    *(int4*)gs = *(const int4*)&G[base];
    short ws8[8];
    #pragma unroll
    for (int j = 0; j < 8; j++) ws8[j] = f2bf(S[j]);
    *(int4*)&G[base] = *(int4*)ws8;
    float dec = expf(acsb[((size_t)(b * SEQL + c * CHUNK + 63)) * HEADS + h]);
    #pragma unroll
    for (int j = 0; j < 8; j++) S[j] = S[j] * dec + b2f(gs[j]);
  }
}

// ------- fused Y = Ydiag + ea_l*Yoff + D*xs, BOTH batches (grid 2048) ------
__global__ __launch_bounds__(256) void y_fused_k(const short* __restrict__ convb,
                                                 const short* __restrict__ CBb,
                                                 const short* __restrict__ G0,
                                                 const short* __restrict__ G1,
                                                 const float* __restrict__ dtb,
                                                 const float* __restrict__ acsb,
                                                 const float* __restrict__ D_skip,
                                                 float* __restrict__ Y) {
  int blk = blockIdx.x & 1023;     // c*HEADS + h
  int b = blockIdx.x >> 10;
  const short* G = b ? G1 : G0;
  int h = blk & 31, c = blk >> 5;
  __shared__ __align__(16) short sM[64][72];    // M(l,s) bf16, plain cols
  __shared__ __align__(16) short sXT[64][72];   // [p][l-swz] = xs(l,p)
  __shared__ float sacs[64], sdt[64], sea[64];
  int t = threadIdx.x;
  int lane = t & 63, w = t >> 6;
  size_t rowb = ((size_t)(b * SEQL + c * CHUNK)) * CONV_DIMN;
  size_t ab = ((size_t)(b * SEQL + c * CHUNK)) * HEADS;
  size_t cbbase = ((size_t)(b * NC + c)) * 64 * 64;
  if (t < 64) {
    float a = acsb[ab + (size_t)t * HEADS + h];
    sacs[t] = a;
    sea[t] = expf(a);
    sdt[t] = dtb[ab + (size_t)t * HEADS + h];
  }
  __syncthreads();
  // stage M(l,s) = CB * exp(acs_l - acs_s) * dt_s * [s<=l]
  #pragma unroll
  for (int i = 0; i < 16; i++) {
    int e = t + 256 * i;
    int r = e >> 6, col = e & 63;
    float m = 0.f;
    if (col <= r)
      m = b2f(CBb[cbbase + (size_t)r * 64 + col]) * expf(sacs[r] - sacs[col]) * sdt[col];
    sM[r][col] = f2bf(m);
  }
  // stage xs^T (raw)
  #pragma unroll
  for (int i = 0; i < 4; i++) {
    int e = t + 256 * i;
    int l = e >> 4, p4 = (e & 15) * 4;
    short4v v = *(const short4v*)&convb[rowb + (size_t)l * CONV_DIMN + h * HEAD_DIM + p4];
    short vv[4] = {v.x, v.y, v.z, v.w};
    #pragma unroll
    for (int j = 0; j < 4; j++) {
      int p = p4 + j;
      sXT[p][((((l >> 3) ^ ((p >> 2) & 7)) << 3) | (l & 7))] = vv[j];
    }
  }
  __syncthreads();
  int mr = lane & 15, q = lane >> 4;
  int wm = (w & 1) * 32, wn = (w >> 1) * 32;
  f32x4 acc1[2][2] = {}, acc2[2][2] = {};
  // MFMA1: Ydiag
  #pragma unroll
  for (int ks = 0; ks < 2; ks++) {
    short8 af[2], bfr[2];
    #pragma unroll
    for (int mi = 0; mi < 2; mi++)
      af[mi] = *(const short8*)&sM[wm + mi * 16 + mr][ks * 32 + q * 8];
    #pragma unroll
    for (int ni = 0; ni < 2; ni++) {
      int p = wn + ni * 16 + mr;
      bfr[ni] = *(const short8*)&sXT[p][(((ks * 4 + q) ^ ((p >> 2) & 7)) << 3)];
    }
    #pragma unroll
    for (int mi = 0; mi < 2; mi++)
      #pragma unroll
      for (int ni = 0; ni < 2; ni++)
        acc1[mi][ni] = __builtin_amdgcn_mfma_f32_16x16x32_bf16(af[mi], bfr[ni], acc1[mi][ni], 0, 0, 0);
  }
  // MFMA2: Yoff/ea -- operands direct from global (raw C rows, S rows)
  const short* Crow = convb + rowb + (D_MODEL + STATE);
  size_t gbase = (size_t)blk * (64 * 256);
  #pragma unroll
  for (int st = 0; st < 8; st++) {
    short8 af[2], bfr[2];
    #pragma unroll
    for (int mi = 0; mi < 2; mi++) {
      int l = wm + mi * 16 + mr;
      af[mi] = *(const short8*)&Crow[(size_t)l * CONV_DIMN + st * 32 + q * 8];
    }
    #pragma unroll
    for (int ni = 0; ni < 2; ni++) {
      int p = wn + ni * 16 + mr;
      bfr[ni] = *(const short8*)&G[gbase + (size_t)p * 256 + st * 32 + q * 8];
    }
    #pragma unroll
    for (int mi = 0; mi < 2; mi++)
      #pragma unroll
      for (int ni = 0; ni < 2; ni++)
        acc2[mi][ni] = __builtin_amdgcn_mfma_f32_16x16x32_bf16(af[mi], bfr[ni], acc2[mi][ni], 0, 0, 0);
  }
  // epilogue
  float dsk = D_skip[h];
  size_t ybase = ((size_t)(b * SEQL + c * CHUNK)) * D_MODEL + h * HEAD_DIM;
  #pragma unroll
  for (int mi = 0; mi < 2; mi++)
    #pragma unroll
    for (int ni = 0; ni < 2; ni++) {
      int p = wn + ni * 16 + mr;
      #pragma unroll
      for (int r = 0; r < 4; r++) {
        int l = wm + mi * 16 + q * 4 + r;
        float xsv = b2f(sXT[p][((((l >> 3) ^ ((p >> 2) & 7)) << 3) | (l & 7))]);
        Y[ybase + (size_t)l * D_MODEL + p] =
            acc1[mi][ni][r] + sea[l] * acc2[mi][ni][r] + dsk * xsv;
      }
    }
}

// ---------------- gated RMSNorm -> bf16 (z from projb) ---------------------
__global__ __launch_bounds__(256) void gated_norm_bf16_k(const float* __restrict__ Y,
                                                         const short* __restrict__ projb,
                                                         const float* __restrict__ gw,
                                                         short* __restrict__ out) {
  int row = blockIdx.x;
  int t = threadIdx.x;
  const float4* y4 = (const float4*)(Y + (size_t)row * D_MODEL);
  float4 ya = y4[2 * t], yb = y4[2 * t + 1];
  short zt[8];
  *(int4*)zt = *(const int4*)(projb + (size_t)row * PROJB_W + t * 8);
  float g[8];
  float yv[8] = {ya.x, ya.y, ya.z, ya.w, yb.x, yb.y, yb.z, yb.w};
  float ss = 0.f;
  #pragma unroll
  for (int i = 0; i < 8; i++) {
    float z = b2f(zt[i]);
    g[i] = yv[i] * (z / (1.f + expf(-z)));
    ss += g[i] * g[i];
  }
  #pragma unroll
  for (int off = 32; off > 0; off >>= 1) ss += __shfl_down(ss, off);
  __shared__ float ws_[4];
  if ((t & 63) == 0) ws_[t >> 6] = ss;
  __syncthreads();
  float tot = ws_[0] + ws_[1] + ws_[2] + ws_[3];
  float scale = rsqrtf(tot / (float)D_MODEL + EPSF);
  const float4* g4 = (const float4*)gw;
  float4 wa = g4[2 * t], wb = g4[2 * t + 1];
  float wv[8] = {wa.x, wa.y, wa.z, wa.w, wb.x, wb.y, wb.z, wb.w};
  short tmp[8];
  #pragma unroll
  for (int i = 0; i < 8; i++) tmp[i] = f2bf(g[i] * scale * wv[i]);
  *(int4*)(out + (size_t)row * D_MODEL + t * 8) = *(int4*)tmp;
}

extern "C" void kernel_launch(void* const* d_in, const int* in_sizes, int n_in,
                              void* d_out, int out_size, void* d_ws, size_t ws_size,
                              hipStream_t stream) {
  const float* x       = (const float*)d_in[0];
  const float* norm_w  = (const float*)d_in[1];
  const float* w_in    = (const float*)d_in[2];
  const float* conv_w  = (const float*)d_in[3];
  const float* conv_b  = (const float*)d_in[4];
  const float* dt_bias = (const float*)d_in[5];
  const float* A_log   = (const float*)d_in[6];
  const float* D_skip  = (const float*)d_in[7];
  const float* gnorm_w = (const float*)d_in[8];
  const float* w_out   = (const float*)d_in[9];
  const float* wo_w    = (const float*)d_in[10];
  float* out = (float*)d_out;

  // workspace (float units), total 36,700,160 fu = 140 MiB
  float* ws    = (float*)d_ws;
  short* xnb   = (short*)ws;                 // [0 .. 4,194,304 fu)  bf16 4096x2048
  short* w_inT = (short*)(ws + 4194304);     // 4,718,592 fu         bf16 4608x2048
  short* projb = (short*)(ws + 8912896);     // 9,437,184 fu         bf16 4096x4608
  short* convb = (short*)(ws + 18350080);    // 5,242,880 fu         bf16 4096x2560
  float* dtraw = ws + 23592960;              // 131,072
  float* dtb   = ws + 23724032;              // 131,072
  float* acsb  = ws + 23855104;              // 131,072
  short* CBb   = (short*)(ws + 23986176);    // 131,072 fu           bf16 64x64x64
  float* Yb    = ws + 24117248;              // 8,388,608
  short* w_outT= (short*)(ws + 32505856);    // 2,097,152 fu
  short* wo_wT = (short*)(ws + 34603008);    // 2,097,152 fu
  short* wdtT  = (short*)dtb;                // 32x2048 bf16 parked in dtb (written later)
  short* G0    = (short*)ws;                 // batch-0 states over xnb+w_inT (dead after big GEMM)
  short* G1    = (short*)out;                // batch-1 states: d_out dead until final GEMM
  short* Yg    = convb;                      // overlays convb after y_fused
  short* t1b   = (short*)ws;                 // overlays G0 region after y_fused

  rmsnorm_bf16_k<<<BL, 256, 0, stream>>>(x, norm_w, xnb);
  transpose_bf16_k<<<dim3(PROJB_W / 32, D_MODEL / 32), 256, 0, stream>>>(w_in, w_inT, D_MODEL, PROJB_W, PROJ_DIM);
  transpose_bf16_k<<<dim3(1, D_MODEL / 32), 256, 0, stream>>>(w_in + D_MODEL + CONV_DIMN, wdtT, D_MODEL, HEADS, PROJ_DIM);
  transpose_bf16_k<<<dim3(D_MODEL / 32, D_MODEL / 32), 256, 0, stream>>>(w_out, w_outT, D_MODEL, D_MODEL, D_MODEL);
  transpose_bf16_k<<<dim3(D_MODEL / 32, D_MODEL / 32), 256, 0, stream>>>(wo_w, wo_wT, D_MODEL, D_MODEL, D_MODEL);
  dtg_k<<<BL / 32, 256, 0, stream>>>(xnb, wdtT, dtraw);
  gemm128_k<true><<<(BL / 128) * (PROJB_W / 256), 512, 0, stream>>>(xnb, w_inT, projb, BL, PROJB_W, D_MODEL);
  conv_silu_k<<<(BL * (CONV_DIMN / 8)) / 256, 256, 0, stream>>>(projb, conv_w, conv_b, convb);
  dt_acs_k<<<BATCHN * NC, 256, 0, stream>>>(dtraw, dt_bias, A_log, dtb, acsb);
  cb_k<<<BATCHN * NC, 256, 0, stream>>>(convb, CBb);
  chunk_states_k<<<BATCHN * NC * HEADS, 256, 0, stream>>>(convb, dtb, acsb, G0, G1);
  scan_states_k<<<512, 256, 0, stream>>>(G0, G1, acsb);
  y_fused_k<<<BATCHN * NC * HEADS, 256, 0, stream>>>(convb, CBb, G0, G1, dtb, acsb, D_skip, Yb);
  gated_norm_bf16_k<<<BL, 256, 0, stream>>>(Yb, projb, gnorm_w, Yg);
  gemm_t128_k<true><<<(BL / 128) * (D_MODEL / 128), 256, 0, stream>>>(Yg, w_outT, t1b, BL, D_MODEL, D_MODEL);
  gemm_t128_k<false><<<(BL / 128) * (D_MODEL / 128), 256, 0, stream>>>(t1b, wo_wT, out, BL, D_MODEL, D_MODEL);
}

// Round 8
// 563.432 us; speedup vs baseline: 1.0763x; 1.0131x over previous
//
#include <hip/hip_runtime.h>
#include <math.h>

#define D_MODEL 2048
#define HEADS 32
#define HEAD_DIM 64
#define STATE 256
#define KCONV 4
#define CHUNK 64
#define NC 32            // SEQ / CHUNK
#define SEQL 2048
#define BATCHN 2
#define CONV_DIMN 2560   // D_MODEL + 2*STATE
#define PROJ_DIM 4640    // D_MODEL + CONV_DIM + HEADS
#define PROJB_W 4608     // 36*128: z + xBC cols (dt handled by dtg_k)
#define EPSF 1e-5f
#define BL (BATCHN * SEQL)  // 4096 token rows

typedef __attribute__((ext_vector_type(8))) short short8;
typedef __attribute__((ext_vector_type(4))) short short4v;
typedef __attribute__((ext_vector_type(4))) float f32x4;

__device__ __forceinline__ short f2bf(float f) {
  unsigned u = __builtin_bit_cast(unsigned, f);
  u = (u + 0x7fffu + ((u >> 16) & 1u)) >> 16;   // RNE
  return (short)u;
}
__device__ __forceinline__ float b2f(short s) {
  unsigned u = ((unsigned)(unsigned short)s) << 16;
  return __builtin_bit_cast(float, u);
}
__device__ __forceinline__ void gld16(const void* g, void* l) {
  __builtin_amdgcn_global_load_lds((const __attribute__((address_space(1))) unsigned int*)g,
                                   (__attribute__((address_space(3))) unsigned int*)l,
                                   16, 0, 0);
}

// ---------------- RMSNorm -> bf16 ------------------------------------------
__global__ __launch_bounds__(256) void rmsnorm_bf16_k(const float* __restrict__ x,
                                                      const float* __restrict__ w,
                                                      short* __restrict__ out) {
  int row = blockIdx.x;
  int t = threadIdx.x;
  const float4* x4 = (const float4*)(x + (size_t)row * D_MODEL);
  float4 va = x4[2 * t], vb = x4[2 * t + 1];
  float ss = va.x * va.x + va.y * va.y + va.z * va.z + va.w * va.w +
             vb.x * vb.x + vb.y * vb.y + vb.z * vb.z + vb.w * vb.w;
  #pragma unroll
  for (int off = 32; off > 0; off >>= 1) ss += __shfl_down(ss, off);
  __shared__ float ws_[4];
  if ((t & 63) == 0) ws_[t >> 6] = ss;
  __syncthreads();
  float tot = ws_[0] + ws_[1] + ws_[2] + ws_[3];
  float scale = rsqrtf(tot / (float)D_MODEL + EPSF);
  const float4* w4 = (const float4*)w;
  float4 wa = w4[2 * t], wb = w4[2 * t + 1];
  short tmp[8];
  tmp[0] = f2bf(va.x * scale * wa.x); tmp[1] = f2bf(va.y * scale * wa.y);
  tmp[2] = f2bf(va.z * scale * wa.z); tmp[3] = f2bf(va.w * scale * wa.w);
  tmp[4] = f2bf(vb.x * scale * wb.x); tmp[5] = f2bf(vb.y * scale * wb.y);
  tmp[6] = f2bf(vb.z * scale * wb.z); tmp[7] = f2bf(vb.w * scale * wb.w);
  *(int4*)(out + (size_t)row * D_MODEL + t * 8) = *(int4*)tmp;
}

// ---------------- transpose + fp32->bf16 -----------------------------------
__global__ __launch_bounds__(256) void transpose_bf16_k(const float* __restrict__ W,
                                                        short* __restrict__ WT,
                                                        int K, int ncols, int stride) {
  __shared__ float tile[32][33];
  int bn = blockIdx.x * 32, bk = blockIdx.y * 32;
  int tx = threadIdx.x & 31, ty = threadIdx.x >> 5;  // ty 0..7
  #pragma unroll
  for (int i = 0; i < 32; i += 8) {
    int k = bk + ty + i, n = bn + tx;
    tile[ty + i][tx] = (n < ncols) ? W[(size_t)k * stride + n] : 0.f;
  }
  __syncthreads();
  #pragma unroll
  for (int i = 0; i < 32; i += 8) {
    int n = bn + ty + i, k = bk + tx;
    if (n < ncols) WT[(size_t)n * K + k] = f2bf(tile[tx][ty + i]);
  }
}

// ------- skinny MFMA dt projection: dtraw = xnb @ WdtT^T (fp32 out) --------
__global__ __launch_bounds__(256) void dtg_k(const short* __restrict__ xnb,
                                             const short* __restrict__ wdtT,
                                             float* __restrict__ dtraw) {
  __shared__ float red[4][32][32];
  int t = threadIdx.x;
  int lane = t & 63, w = t >> 6;
  int mr = lane & 15, q = lane >> 4;
  int m0 = blockIdx.x * 32;
  f32x4 acc[2][2] = {};
  for (int ks = 0; ks < 16; ks++) {
    int k = w * 512 + ks * 32 + q * 8;
    short8 af[2], bfr[2];
    #pragma unroll
    for (int i = 0; i < 2; i++)
      af[i] = *(const short8*)&xnb[(size_t)(m0 + i * 16 + mr) * D_MODEL + k];
    #pragma unroll
    for (int i = 0; i < 2; i++)
      bfr[i] = *(const short8*)&wdtT[(size_t)(i * 16 + mr) * D_MODEL + k];
    #pragma unroll
    for (int mi = 0; mi < 2; mi++)
      #pragma unroll
      for (int ni = 0; ni < 2; ni++)
        acc[mi][ni] = __builtin_amdgcn_mfma_f32_16x16x32_bf16(af[mi], bfr[ni], acc[mi][ni], 0, 0, 0);
  }
  #pragma unroll
  for (int mi = 0; mi < 2; mi++)
    #pragma unroll
    for (int ni = 0; ni < 2; ni++)
      #pragma unroll
      for (int r = 0; r < 4; r++)
        red[w][mi * 16 + q * 4 + r][ni * 16 + mr] = acc[mi][ni][r];
  __syncthreads();
  #pragma unroll
  for (int i = 0; i < 4; i++) {
    int e = t + 256 * i;
    int row = e >> 5, col = e & 31;
    dtraw[(size_t)(m0 + row) * HEADS + col] =
        red[0][row][col] + red[1][row][col] + red[2][row][col] + red[3][row][col];
  }
}

// ---------------- pipelined MFMA GEMM: C[M,N] = A[M,K] @ BT[N,K]^T ---------
// Tile 128x256, BK=32, 8 waves, 3-buffer rotation, dist-2 prefetch, counted
// vmcnt (LPT=3), raw s_barrier, setprio, XCD swizzle. 72 KiB -> 2 blocks/CU
// = 16 waves/CU (the proven stall-hiding operating point, 745 TF).
template<bool BF16OUT>
__global__ __launch_bounds__(512, 4) void gemm128_k(const short* __restrict__ A,
                                                    const short* __restrict__ BT,
                                                    void* __restrict__ Cout,
                                                    int M, int N, int K) {
  constexpr int ABUF = 128 * 32;        // shorts per A buffer
  constexpr int BUFS = ABUF + 8192;     // + B 256x32 shorts = 12288 shorts
  constexpr int LPT = 3;                // gld16 per tile per thread (A1 + B2)
  __shared__ short lds[3 * BUFS];       // 72 KiB

  const int t = threadIdx.x;
  const int lane = t & 63, w = t >> 6;
  const int mr = lane & 15, q = lane >> 4;
  const int cq8 = (q ^ ((mr >> 1) & 3)) * 8;            // read k-chunk (swizzled)
  const int stj = ((lane & 3) ^ ((lane >> 3) & 3)) * 8; // stage global k-chunk
  const int str = lane >> 2;                            // stage row within 16

  // bijective XCD swizzle (all grids here are %8==0)
  const int nbx = N >> 8;
  const int nwg = nbx * (M >> 7);
  const int cpx = nwg >> 3;
  const int bid = blockIdx.x;
  const int swz = (bid & 7) * cpx + (bid >> 3);
  const int bx = swz % nbx, by = swz / nbx;
  const int m0 = by * 128, n0 = bx * 256;

  const int NT = K >> 5;   // assumes NT >= 3 (all call sites K=2048)
  f32x4 acc[8][2] = {};

  auto STAGE = [&](int tile, int buf) {
    short* dst = &lds[buf * BUFS];
    const int kb = tile * 32 + stj;
    gld16(A + (size_t)(m0 + w * 16 + str) * K + kb, dst + w * 512);
    const short* gB = BT + (size_t)(n0 + w * 32 + str) * K + kb;
    short* dB = dst + ABUF + w * 1024;
    gld16(gB, dB);
    gld16(gB + (size_t)16 * K, dB + 512);
  };

  STAGE(0, 0); STAGE(1, 1);
  asm volatile("s_waitcnt vmcnt(%0)" :: "n"(LPT) : "memory");
  __builtin_amdgcn_s_barrier();

  int bufc = 0;
  for (int tt = 0; tt < NT; ++tt) {
    const short* sA = &lds[bufc * BUFS];
    const short* sB = sA + ABUF;
    if (tt + 2 < NT) STAGE(tt + 2, bufc >= 1 ? bufc - 1 : 2);
    short8 af[4], bfr[2];
    #pragma unroll
    for (int ni = 0; ni < 2; ni++)
      bfr[ni] = *(const short8*)&sB[(w * 32 + ni * 16 + mr) * 32 + cq8];
    #pragma unroll
    for (int mi = 0; mi < 4; mi++)
      af[mi] = *(const short8*)&sA[(mi * 16 + mr) * 32 + cq8];
    __builtin_amdgcn_s_setprio(1);
    #pragma unroll
    for (int mi = 0; mi < 4; mi++)
      #pragma unroll
      for (int ni = 0; ni < 2; ni++)
        acc[mi][ni] = __builtin_amdgcn_mfma_f32_16x16x32_bf16(af[mi], bfr[ni], acc[mi][ni], 0, 0, 0);
    __builtin_amdgcn_s_setprio(0);
    #pragma unroll
    for (int mi = 0; mi < 4; mi++)
      af[mi] = *(const short8*)&sA[(64 + mi * 16 + mr) * 32 + cq8];
    __builtin_amdgcn_s_setprio(1);
    #pragma unroll
    for (int mi = 0; mi < 4; mi++)
      #pragma unroll
      for (int ni = 0; ni < 2; ni++)
        acc[4 + mi][ni] = __builtin_amdgcn_mfma_f32_16x16x32_bf16(af[mi], bfr[ni], acc[4 + mi][ni], 0, 0, 0);
    __builtin_amdgcn_s_setprio(0);
    __builtin_amdgcn_sched_barrier(0);
    if (tt + 2 < NT) asm volatile("s_waitcnt vmcnt(%0)" :: "n"(LPT) : "memory");
    else             asm volatile("s_waitcnt vmcnt(0)" ::: "memory");
    __builtin_amdgcn_s_barrier();
    bufc = (bufc == 2) ? 0 : bufc + 1;
  }

  #pragma unroll
  for (int mi = 0; mi < 8; mi++)
    #pragma unroll
    for (int ni = 0; ni < 2; ni++) {
      const int gm = m0 + mi * 16 + q * 4;
      const int gn = n0 + w * 32 + ni * 16 + mr;
      #pragma unroll
      for (int r = 0; r < 4; r++) {
        if (BF16OUT) ((short*)Cout)[(size_t)(gm + r) * N + gn] = f2bf(acc[mi][ni][r]);
        else         ((float*)Cout)[(size_t)(gm + r) * N + gn] = acc[mi][ni][r];
      }
    }
}

// ------- 128x128-tile 8-wave variant for the N=2048 tail GEMMs -------------
// Same schedule/swizzle/hazard structure as gemm128_k.  8 waves (512 thr),
// wave grid 2M x 4N (per-wave 64x32), LPT=2 (1 A + 1 B gld16/thread), LDS
// 3 x 16 KiB = 48 KiB -> 2 blocks/CU = 16 waves/CU -- the SAME occupancy
// point as the proven big GEMM (round-7 showed 4-wave/12-waves-per-CU and
// 8-wave/8-waves-per-CU tails are equally sub-plateau; waves/CU is the
// currency for hiding the 2-phase stage+barrier stalls, not reads/MFMA).
// Tail grid = 32 x 16 = 512 blocks = exactly 2/CU, zero remainder.
template<bool BF16OUT>
__global__ __launch_bounds__(512, 4) void gemm_s128_k(const short* __restrict__ A,
                                                      const short* __restrict__ BT,
                                                      void* __restrict__ Cout,
                                                      int M, int N, int K) {
  constexpr int ABUF = 128 * 32;        // 4096 shorts
  constexpr int BUFS = ABUF + 128 * 32; // 8192 shorts (16 KiB)
  constexpr int LPT = 2;                // gld16 per tile per thread (A1 + B1)
  __shared__ short lds[3 * BUFS];       // 48 KiB

  const int t = threadIdx.x;
  const int lane = t & 63, w = t >> 6;  // 8 waves
  const int mr = lane & 15, q = lane >> 4;
  const int cq8 = (q ^ ((mr >> 1) & 3)) * 8;
  const int stj = ((lane & 3) ^ ((lane >> 3) & 3)) * 8;
  const int str = lane >> 2;
  const int wm = w & 1, wn = w >> 1;    // 2M x 4N wave grid

  // bijective XCD swizzle (grids %8==0)
  const int nbx = N >> 7;
  const int nwg = nbx * (M >> 7);
  const int cpx = nwg >> 3;
  const int bid = blockIdx.x;
  const int swz = (bid & 7) * cpx + (bid >> 3);
  const int bx = swz % nbx, by = swz / nbx;
  const int m0 = by * 128, n0 = bx * 128;

  const int NT = K >> 5;
  f32x4 acc[4][2] = {};

  auto STAGE = [&](int tile, int buf) {
    short* dst = &lds[buf * BUFS];
    const int kb = tile * 32 + stj;
    gld16(A + (size_t)(m0 + w * 16 + str) * K + kb, dst + w * 512);
    gld16(BT + (size_t)(n0 + w * 16 + str) * K + kb, dst + ABUF + w * 512);
  };

  STAGE(0, 0); STAGE(1, 1);
  asm volatile("s_waitcnt vmcnt(%0)" :: "n"(LPT) : "memory");
  __builtin_amdgcn_s_barrier();

  int bufc = 0;
  for (int tt = 0; tt < NT; ++tt) {
    const short* sA = &lds[bufc * BUFS];
    const short* sB = sA + ABUF;
    if (tt + 2 < NT) STAGE(tt + 2, bufc >= 1 ? bufc - 1 : 2);
    short8 af[4], bfr[2];
    #pragma unroll
    for (int ni = 0; ni < 2; ni++)
      bfr[ni] = *(const short8*)&sB[(wn * 32 + ni * 16 + mr) * 32 + cq8];
    #pragma unroll
    for (int mi = 0; mi < 4; mi++)
      af[mi] = *(const short8*)&sA[(wm * 64 + mi * 16 + mr) * 32 + cq8];
    __builtin_amdgcn_s_setprio(1);
    #pragma unroll
    for (int mi = 0; mi < 4; mi++)
      #pragma unroll
      for (int ni = 0; ni < 2; ni++)
        acc[mi][ni] = __builtin_amdgcn_mfma_f32_16x16x32_bf16(af[mi], bfr[ni], acc[mi][ni], 0, 0, 0);
    __builtin_amdgcn_s_setprio(0);
    __builtin_amdgcn_sched_barrier(0);
    if (tt + 2 < NT) asm volatile("s_waitcnt vmcnt(%0)" :: "n"(LPT) : "memory");
    else             asm volatile("s_waitcnt vmcnt(0)" ::: "memory");
    __builtin_amdgcn_s_barrier();
    bufc = (bufc == 2) ? 0 : bufc + 1;
  }

  #pragma unroll
  for (int mi = 0; mi < 4; mi++)
    #pragma unroll
    for (int ni = 0; ni < 2; ni++) {
      const int gm = m0 + wm * 64 + mi * 16 + q * 4;
      const int gn = n0 + wn * 32 + ni * 16 + mr;
      #pragma unroll
      for (int r = 0; r < 4; r++) {
        if (BF16OUT) ((short*)Cout)[(size_t)(gm + r) * N + gn] = f2bf(acc[mi][ni][r]);
        else         ((float*)Cout)[(size_t)(gm + r) * N + gn] = acc[mi][ni][r];
      }
    }
}

// ------- depthwise causal conv + bias + SiLU, 8-channel vectorized ---------
__global__ __launch_bounds__(256) void conv_silu_k(const short* __restrict__ projb,
                                                   const float* __restrict__ cw,
                                                   const float* __restrict__ cb,
                                                   short* __restrict__ out) {
  int idx = blockIdx.x * 256 + threadIdx.x;   // BL * (CONV_DIM/8) total
  int ci = idx % (CONV_DIMN / 8);
  int bt = idx / (CONV_DIMN / 8);
  int t = bt & (SEQL - 1);
  int b = bt >> 11;
  int c = ci * 8;
  float4 w4[8];
  #pragma unroll
  for (int j = 0; j < 8; j++) w4[j] = ((const float4*)cw)[c + j];
  float acc[8];
  {
    float4 b0 = ((const float4*)(cb + c))[0], b1 = ((const float4*)(cb + c))[1];
    acc[0] = b0.x; acc[1] = b0.y; acc[2] = b0.z; acc[3] = b0.w;
    acc[4] = b1.x; acc[5] = b1.y; acc[6] = b1.z; acc[7] = b1.w;
  }
  #pragma unroll
  for (int k = 0; k < KCONV; k++) {
    int tt = t - (KCONV - 1) + k;
    if (tt < 0) continue;
    short8 v = *(const short8*)&projb[((size_t)(b * SEQL + tt)) * PROJB_W + D_MODEL + c];
    #pragma unroll
    for (int j = 0; j < 8; j++) {
      float wv = (k == 0) ? w4[j].x : (k == 1) ? w4[j].y : (k == 2) ? w4[j].z : w4[j].w;
      acc[j] += b2f(v[j]) * wv;
    }
  }
  short o[8];
  #pragma unroll
  for (int j = 0; j < 8; j++) o[j] = f2bf(acc[j] / (1.f + expf(-acc[j])));
  *(int4*)&out[(size_t)bt * CONV_DIMN + c] = *(int4*)o;
}

// ------- merged CB + dt softplus/cumsum (both 64-block kernels; branch is
// block-uniform so the in-branch __syncthreads is safe).  Overlaps two
// low-occupancy kernels that previously ran back-to-back. ----------------
__global__ __launch_bounds__(256) void cbdt_k(const short* __restrict__ convb,
                                              short* __restrict__ CB,
                                              const float* __restrict__ dtraw,
                                              const float* __restrict__ dt_bias,
                                              const float* __restrict__ A_log,
                                              float* __restrict__ dtb,
                                              float* __restrict__ acsb) {
  if (blockIdx.x < BATCHN * NC) {
    // ---- CB[b,c,l,s] = sum_n C(l,n)*B(s,n) -> bf16 ----
    int bc = blockIdx.x;
    int b = bc / NC, c = bc % NC;
    __shared__ float sC[64][65];
    __shared__ float sB[64][65];
    int t = threadIdx.x;
    int s = t & 63;
    int lb = (t >> 6) * 16;
    float acc[16] = {};
    size_t rowb = ((size_t)(b * SEQL + c * CHUNK)) * CONV_DIMN;
    for (int nt = 0; nt < 4; nt++) {
      __syncthreads();
      #pragma unroll
      for (int i = 0; i < 16; i++) {
        int e = t + 256 * i;
        int r = e >> 6, col = e & 63;
        sC[r][col] = b2f(convb[rowb + (size_t)r * CONV_DIMN + (D_MODEL + STATE) + nt * 64 + col]);
        sB[r][col] = b2f(convb[rowb + (size_t)r * CONV_DIMN + D_MODEL + nt * 64 + col]);
      }
      __syncthreads();
      for (int n = 0; n < 64; n++) {
        float bv = sB[s][n];
        #pragma unroll
        for (int j = 0; j < 16; j++) acc[j] += sC[lb + j][n] * bv;
      }
    }
    size_t ob = ((size_t)bc) * 64 * 64;
    #pragma unroll
    for (int j = 0; j < 16; j++) CB[ob + (size_t)(lb + j) * 64 + s] = f2bf(acc[j]);
  } else {
    // ---- dt softplus + per-chunk cumsum of A*dt ----
    int bc = blockIdx.x - BATCHN * NC;
    int b = bc / NC, c = bc % NC;
    int t = threadIdx.x;
    int l = t & 63, w = t >> 6;   // wave w handles heads w*8..w*8+7
    size_t base = ((size_t)(b * SEQL + c * CHUNK + l)) * HEADS;
    #pragma unroll
    for (int i = 0; i < 8; i++) {
      int h = w * 8 + i;
      float raw = dtraw[base + h] + dt_bias[h];
      float dt = raw > 20.f ? raw : log1pf(expf(raw));
      float adt = -expf(A_log[h]) * dt;
      float cs = adt;
      #pragma unroll
      for (int off = 1; off < 64; off <<= 1) {
        float v = __shfl_up(cs, off);
        if (l >= off) cs += v;
      }
      dtb[base + h] = dt;
      acsb[base + h] = cs;
    }
  }
}

// ------- chunk states via MFMA, BOTH batches in one launch (grid 2048) -----
__global__ __launch_bounds__(256) void chunk_states_k(const short* __restrict__ convb,
                                                      const float* __restrict__ dtb,
                                                      const float* __restrict__ acsb,
                                                      short* __restrict__ G0,
                                                      short* __restrict__ G1) {
  int blk = blockIdx.x & 1023;     // c*HEADS + h
  int b = blockIdx.x >> 10;
  short* G = b ? G1 : G0;
  int h = blk & 31, c = blk >> 5;
  __shared__ __align__(16) short sXT[64][72];   // [p][l-swz] = bf16(xs(l,p)*wt(l))
  __shared__ __align__(16) short sBT[256][72];  // [n][l-swz] = B(l,n)
  __shared__ float swt[64];
  int t = threadIdx.x;
  size_t rowb = ((size_t)(b * SEQL + c * CHUNK)) * CONV_DIMN;
  size_t ab = ((size_t)(b * SEQL + c * CHUNK)) * HEADS;
  if (t < 64) {
    float a = acsb[ab + (size_t)t * HEADS + h];
    float alast = acsb[ab + (size_t)63 * HEADS + h];
    swt[t] = expf(alast - a) * dtb[ab + (size_t)t * HEADS + h];
  }
  __syncthreads();
  #pragma unroll
  for (int i = 0; i < 4; i++) {
    int e = t + 256 * i;
    int l = e >> 4, p4 = (e & 15) * 4;
    short4v v = *(const short4v*)&convb[rowb + (size_t)l * CONV_DIMN + h * HEAD_DIM + p4];
    float wt = swt[l];
    short vv[4] = {v.x, v.y, v.z, v.w};
    #pragma unroll
    for (int j = 0; j < 4; j++) {
      int p = p4 + j;
      sXT[p][((((l >> 3) ^ ((p >> 2) & 7)) << 3) | (l & 7))] = f2bf(b2f(vv[j]) * wt);
    }
  }
  #pragma unroll
  for (int i = 0; i < 16; i++) {
    int e = t + 256 * i;
    int l = e >> 6, n4 = (e & 63) * 4;
    short4v v = *(const short4v*)&convb[rowb + (size_t)l * CONV_DIMN + D_MODEL + n4];
    short vv[4] = {v.x, v.y, v.z, v.w};
    #pragma unroll
    for (int j = 0; j < 4; j++) {
      int n = n4 + j;
      sBT[n][((((l >> 3) ^ ((n >> 2) & 7)) << 3) | (l & 7))] = vv[j];
    }
  }
  __syncthreads();
  int lane = t & 63, w = t >> 6;
  int mr = lane & 15, q = lane >> 4;
  f32x4 acc[4][4] = {};
  #pragma unroll
  for (int ks = 0; ks < 2; ks++) {
    short8 af[4], bfr[4];
    #pragma unroll
    for (int mi = 0; mi < 4; mi++) {
      int p = mi * 16 + mr;
      af[mi] = *(const short8*)&sXT[p][(((ks * 4 + q) ^ ((p >> 2) & 7)) << 3)];
    }
    #pragma unroll
    for (int ni = 0; ni < 4; ni++) {
      int n = w * 64 + ni * 16 + mr;
      bfr[ni] = *(const short8*)&sBT[n][(((ks * 4 + q) ^ ((n >> 2) & 7)) << 3)];
    }
    #pragma unroll
    for (int mi = 0; mi < 4; mi++)
      #pragma unroll
      for (int ni = 0; ni < 4; ni++)
        acc[mi][ni] = __builtin_amdgcn_mfma_f32_16x16x32_bf16(af[mi], bfr[ni], acc[mi][ni], 0, 0, 0);
  }
  size_t gb = (size_t)blk * (64 * 256);
  #pragma unroll
  for (int mi = 0; mi < 4; mi++)
    #pragma unroll
    for (int ni = 0; ni < 4; ni++)
      #pragma unroll
      for (int r = 0; r < 4; r++)
        G[gb + (size_t)(mi * 16 + q * 4 + r) * 256 + w * 64 + ni * 16 + mr] = f2bf(acc[mi][ni][r]);
}

// ------- sequential chunk recursion, both batches, int4-vectorized ---------
__global__ __launch_bounds__(256) void scan_states_k(short* __restrict__ G0,
                                                     short* __restrict__ G1,
                                                     const float* __restrict__ acsb) {
  int gid = blockIdx.x * 256 + threadIdx.x;   // 512 blocks = 131072 threads
  int b = gid >> 16;
  int tid = gid & 65535;                       // 65536 threads per batch
  short* G = b ? G1 : G0;
  int n8 = tid & 31, p = (tid >> 5) & 63, h = tid >> 11;
  float S[8] = {};
  for (int c = 0; c < NC; c++) {
    size_t base = (((size_t)(c * HEADS + h) * 64) + p) * 256 + n8 * 8;
    short gs[8];
    *(int4*)gs = *(const int4*)&G[base];
    short ws8[8];
    #pragma unroll
    for (int j = 0; j < 8; j++) ws8[j] = f2bf(S[j]);
    *(int4*)&G[base] = *(int4*)ws8;
    float dec = expf(acsb[((size_t)(b * SEQL + c * CHUNK + 63)) * HEADS + h]);
    #pragma unroll
    for (int j = 0; j < 8; j++) S[j] = S[j] * dec + b2f(gs[j]);
  }
}

// ------- fused Y = Ydiag + ea_l*Yoff + D*xs, BOTH batches (grid 2048) ------
__global__ __launch_bounds__(256) void y_fused_k(const short* __restrict__ convb,
                                                 const short* __restrict__ CBb,
                                                 const short* __restrict__ G0,
                                                 const short* __restrict__ G1,
                                                 const float* __restrict__ dtb,
                                                 const float* __restrict__ acsb,
                                                 const float* __restrict__ D_skip,
                                                 float* __restrict__ Y) {
  int blk = blockIdx.x & 1023;     // c*HEADS + h
  int b = blockIdx.x >> 10;
  const short* G = b ? G1 : G0;
  int h = blk & 31, c = blk >> 5;
  __shared__ __align__(16) short sM[64][72];    // M(l,s) bf16, plain cols
  __shared__ __align__(16) short sXT[64][72];   // [p][l-swz] = xs(l,p)
  __shared__ float sacs[64], sdt[64], sea[64];
  int t = threadIdx.x;
  int lane = t & 63, w = t >> 6;
  size_t rowb = ((size_t)(b * SEQL + c * CHUNK)) * CONV_DIMN;
  size_t ab = ((size_t)(b * SEQL + c * CHUNK)) * HEADS;
  size_t cbbase = ((size_t)(b * NC + c)) * 64 * 64;
  if (t < 64) {
    float a = acsb[ab + (size_t)t * HEADS + h];
    sacs[t] = a;
    sea[t] = expf(a);
    sdt[t] = dtb[ab + (size_t)t * HEADS + h];
  }
  __syncthreads();
  // stage M(l,s) = CB * exp(acs_l - acs_s) * dt_s * [s<=l]
  #pragma unroll
  for (int i = 0; i < 16; i++) {
    int e = t + 256 * i;
    int r = e >> 6, col = e & 63;
    float m = 0.f;
    if (col <= r)
      m = b2f(CBb[cbbase + (size_t)r * 64 + col]) * expf(sacs[r] - sacs[col]) * sdt[col];
    sM[r][col] = f2bf(m);
  }
  // stage xs^T (raw)
  #pragma unroll
  for (int i = 0; i < 4; i++) {
    int e = t + 256 * i;
    int l = e >> 4, p4 = (e & 15) * 4;
    short4v v = *(const short4v*)&convb[rowb + (size_t)l * CONV_DIMN + h * HEAD_DIM + p4];
    short vv[4] = {v.x, v.y, v.z, v.w};
    #pragma unroll
    for (int j = 0; j < 4; j++) {
      int p = p4 + j;
      sXT[p][((((l >> 3) ^ ((p >> 2) & 7)) << 3) | (l & 7))] = vv[j];
    }
  }
  __syncthreads();
  int mr = lane & 15, q = lane >> 4;
  int wm = (w & 1) * 32, wn = (w >> 1) * 32;
  f32x4 acc1[2][2] = {}, acc2[2][2] = {};
  // MFMA1: Ydiag
  #pragma unroll
  for (int ks = 0; ks < 2; ks++) {
    short8 af[2], bfr[2];
    #pragma unroll
    for (int mi = 0; mi < 2; mi++)
      af[mi] = *(const short8*)&sM[wm + mi * 16 + mr][ks * 32 + q * 8];
    #pragma unroll
    for (int ni = 0; ni < 2; ni++) {
      int p = wn + ni * 16 + mr;
      bfr[ni] = *(const short8*)&sXT[p][(((ks * 4 + q) ^ ((p >> 2) & 7)) << 3)];
    }
    #pragma unroll
    for (int mi = 0; mi < 2; mi++)
      #pragma unroll
      for (int ni = 0; ni < 2; ni++)
        acc1[mi][ni] = __builtin_amdgcn_mfma_f32_16x16x32_bf16(af[mi], bfr[ni], acc1[mi][ni], 0, 0, 0);
  }
  // MFMA2: Yoff/ea -- operands direct from global (raw C rows, S rows)
  const short* Crow = convb + rowb + (D_MODEL + STATE);
  size_t gbase = (size_t)blk * (64 * 256);
  #pragma unroll
  for (int st = 0; st < 8; st++) {
    short8 af[2], bfr[2];
    #pragma unroll
    for (int mi = 0; mi < 2; mi++) {
      int l = wm + mi * 16 + mr;
      af[mi] = *(const short8*)&Crow[(size_t)l * CONV_DIMN + st * 32 + q * 8];
    }
    #pragma unroll
    for (int ni = 0; ni < 2; ni++) {
      int p = wn + ni * 16 + mr;
      bfr[ni] = *(const short8*)&G[gbase + (size_t)p * 256 + st * 32 + q * 8];
    }
    #pragma unroll
    for (int mi = 0; mi < 2; mi++)
      #pragma unroll
      for (int ni = 0; ni < 2; ni++)
        acc2[mi][ni] = __builtin_amdgcn_mfma_f32_16x16x32_bf16(af[mi], bfr[ni], acc2[mi][ni], 0, 0, 0);
  }
  // epilogue
  float dsk = D_skip[h];
  size_t ybase = ((size_t)(b * SEQL + c * CHUNK)) * D_MODEL + h * HEAD_DIM;
  #pragma unroll
  for (int mi = 0; mi < 2; mi++)
    #pragma unroll
    for (int ni = 0; ni < 2; ni++) {
      int p = wn + ni * 16 + mr;
      #pragma unroll
      for (int r = 0; r < 4; r++) {
        int l = wm + mi * 16 + q * 4 + r;
        float xsv = b2f(sXT[p][((((l >> 3) ^ ((p >> 2) & 7)) << 3) | (l & 7))]);
        Y[ybase + (size_t)l * D_MODEL + p] =
            acc1[mi][ni][r] + sea[l] * acc2[mi][ni][r] + dsk * xsv;
      }
    }
}

// ---------------- gated RMSNorm -> bf16 (z from projb) ---------------------
__global__ __launch_bounds__(256) void gated_norm_bf16_k(const float* __restrict__ Y,
                                                         const short* __restrict__ projb,
                                                         const float* __restrict__ gw,
                                                         short* __restrict__ out) {
  int row = blockIdx.x;
  int t = threadIdx.x;
  const float4* y4 = (const float4*)(Y + (size_t)row * D_MODEL);
  float4 ya = y4[2 * t], yb = y4[2 * t + 1];
  short zt[8];
  *(int4*)zt = *(const int4*)(projb + (size_t)row * PROJB_W + t * 8);
  float g[8];
  float yv[8] = {ya.x, ya.y, ya.z, ya.w, yb.x, yb.y, yb.z, yb.w};
  float ss = 0.f;
  #pragma unroll
  for (int i = 0; i < 8; i++) {
    float z = b2f(zt[i]);
    g[i] = yv[i] * (z / (1.f + expf(-z)));
    ss += g[i] * g[i];
  }
  #pragma unroll
  for (int off = 32; off > 0; off >>= 1) ss += __shfl_down(ss, off);
  __shared__ float ws_[4];
  if ((t & 63) == 0) ws_[t >> 6] = ss;
  __syncthreads();
  float tot = ws_[0] + ws_[1] + ws_[2] + ws_[3];
  float scale = rsqrtf(tot / (float)D_MODEL + EPSF);
  const float4* g4 = (const float4*)gw;
  float4 wa = g4[2 * t], wb = g4[2 * t + 1];
  float wv[8] = {wa.x, wa.y, wa.z, wa.w, wb.x, wb.y, wb.z, wb.w};
  short tmp[8];
  #pragma unroll
  for (int i = 0; i < 8; i++) tmp[i] = f2bf(g[i] * scale * wv[i]);
  *(int4*)(out + (size_t)row * D_MODEL + t * 8) = *(int4*)tmp;
}

extern "C" void kernel_launch(void* const* d_in, const int* in_sizes, int n_in,
                              void* d_out, int out_size, void* d_ws, size_t ws_size,
                              hipStream_t stream) {
  const float* x       = (const float*)d_in[0];
  const float* norm_w  = (const float*)d_in[1];
  const float* w_in    = (const float*)d_in[2];
  const float* conv_w  = (const float*)d_in[3];
  const float* conv_b  = (const float*)d_in[4];
  const float* dt_bias = (const float*)d_in[5];
  const float* A_log   = (const float*)d_in[6];
  const float* D_skip  = (const float*)d_in[7];
  const float* gnorm_w = (const float*)d_in[8];
  const float* w_out   = (const float*)d_in[9];
  const float* wo_w    = (const float*)d_in[10];
  float* out = (float*)d_out;

  // workspace (float units), total 36,700,160 fu = 140 MiB
  float* ws    = (float*)d_ws;
  short* xnb   = (short*)ws;                 // [0 .. 4,194,304 fu)  bf16 4096x2048
  short* w_inT = (short*)(ws + 4194304);     // 4,718,592 fu         bf16 4608x2048
  short* projb = (short*)(ws + 8912896);     // 9,437,184 fu         bf16 4096x4608
  short* convb = (short*)(ws + 18350080);    // 5,242,880 fu         bf16 4096x2560
  float* dtraw = ws + 23592960;              // 131,072
  float* dtb   = ws + 23724032;              // 131,072
  float* acsb  = ws + 23855104;              // 131,072
  short* CBb   = (short*)(ws + 23986176);    // 131,072 fu           bf16 64x64x64
  float* Yb    = ws + 24117248;              // 8,388,608
  short* w_outT= (short*)(ws + 32505856);    // 2,097,152 fu
  short* wo_wT = (short*)(ws + 34603008);    // 2,097,152 fu
  short* wdtT  = (short*)dtb;                // 32x2048 bf16 parked in dtb (written later)
  short* G0    = (short*)ws;                 // batch-0 states over xnb+w_inT (dead after big GEMM)
  short* G1    = (short*)out;                // batch-1 states: d_out dead until final GEMM
  short* Yg    = convb;                      // overlays convb after y_fused
  short* t1b   = (short*)ws;                 // overlays G0 region after y_fused

  rmsnorm_bf16_k<<<BL, 256, 0, stream>>>(x, norm_w, xnb);
  transpose_bf16_k<<<dim3(PROJB_W / 32, D_MODEL / 32), 256, 0, stream>>>(w_in, w_inT, D_MODEL, PROJB_W, PROJ_DIM);
  transpose_bf16_k<<<dim3(1, D_MODEL / 32), 256, 0, stream>>>(w_in + D_MODEL + CONV_DIMN, wdtT, D_MODEL, HEADS, PROJ_DIM);
  transpose_bf16_k<<<dim3(D_MODEL / 32, D_MODEL / 32), 256, 0, stream>>>(w_out, w_outT, D_MODEL, D_MODEL, D_MODEL);
  transpose_bf16_k<<<dim3(D_MODEL / 32, D_MODEL / 32), 256, 0, stream>>>(wo_w, wo_wT, D_MODEL, D_MODEL, D_MODEL);
  dtg_k<<<BL / 32, 256, 0, stream>>>(xnb, wdtT, dtraw);
  gemm128_k<true><<<(BL / 128) * (PROJB_W / 256), 512, 0, stream>>>(xnb, w_inT, projb, BL, PROJB_W, D_MODEL);
  conv_silu_k<<<(BL * (CONV_DIMN / 8)) / 256, 256, 0, stream>>>(projb, conv_w, conv_b, convb);
  cbdt_k<<<2 * BATCHN * NC, 256, 0, stream>>>(convb, CBb, dtraw, dt_bias, A_log, dtb, acsb);
  chunk_states_k<<<BATCHN * NC * HEADS, 256, 0, stream>>>(convb, dtb, acsb, G0, G1);
  scan_states_k<<<512, 256, 0, stream>>>(G0, G1, acsb);
  y_fused_k<<<BATCHN * NC * HEADS, 256, 0, stream>>>(convb, CBb, G0, G1, dtb, acsb, D_skip, Yb);
  gated_norm_bf16_k<<<BL, 256, 0, stream>>>(Yb, projb, gnorm_w, Yg);
  gemm_s128_k<true><<<(BL / 128) * (D_MODEL / 128), 512, 0, stream>>>(Yg, w_outT, t1b, BL, D_MODEL, D_MODEL);
  gemm_s128_k<false><<<(BL / 128) * (D_MODEL / 128), 512, 0, stream>>>(t1b, wo_wT, out, BL, D_MODEL, D_MODEL);
}